// Round 7
// baseline (345.472 us; speedup 1.0000x reference)
//
#include <hip/hip_runtime.h>

#define N 32
#define C 256
#define HW 1024
#define S 64
#define LOG2E 1.4426950408889634f

typedef _Float16 f16;
typedef _Float16 f16x4 __attribute__((ext_vector_type(4)));
typedef _Float16 f16x8 __attribute__((ext_vector_type(8)));
typedef float f32x4 __attribute__((ext_vector_type(4)));

#define MFMA(a, b, c) __builtin_amdgcn_mfma_f32_16x16x32_f16(a, b, c, 0, 0, 0)
#define EXP2(x) exp2f(x)

// 8B-aligned LDS f16x8 load (two ds_read_b64)
__device__ inline f16x8 lds_ld8(const f16* p) {
    f16x4 a = *(const f16x4*)p;
    f16x4 b = *(const f16x4*)(p + 4);
    f16x8 r;
    r[0] = a[0]; r[1] = a[1]; r[2] = a[2]; r[3] = a[3];
    r[4] = b[0]; r[5] = b[1]; r[6] = b[2]; r[7] = b[3];
    return r;
}

// ---------- pool pass 1 (+ weight conversion fold): float4 stream ----------
__global__ void __launch_bounds__(256) k_pool1(const float* seg, const float* edge,
        f16* segf, float* pms, float* pme, float* mean,
        const float* Ws1, const float* Ws11, const float* Wg, f16* Wf, f16* Wgf) {
    int n = blockIdx.x, cg = blockIdx.y;          // grid (32, 32), 8 c per block
    int t = threadIdx.x, w = t >> 6, lane = t & 63;
    int flat = n * 32 + cg;
    if (flat < 256) {                              // weight conversion fold
        int i = flat * 256 + t;
        if (i < S * C) { Wf[i] = (f16)Ws1[i]; Wf[S * C + i] = (f16)Ws11[i]; }
        Wgf[i] = (f16)Wg[i];
    }
    int p4 = (lane << 2) + (w << 8);
    size_t base = (size_t)n * C * HW;
    float4 ms = make_float4(-3e38f, -3e38f, -3e38f, -3e38f);
    float4 me = ms;
    __shared__ float psum[4][8];
    for (int ci = 0; ci < 8; ci++) {
        int c = cg * 8 + ci;
        size_t off = base + (size_t)c * HW + p4;
        float4 s = *(const float4*)(seg + off);
        float4 e = *(const float4*)(edge + off);
        union { f16 h[4]; unsigned long long u; } pk;
        pk.h[0] = (f16)s.x; pk.h[1] = (f16)s.y; pk.h[2] = (f16)s.z; pk.h[3] = (f16)s.w;
        *(unsigned long long*)(segf + off) = pk.u;
        ms.x = fmaxf(ms.x, s.x); ms.y = fmaxf(ms.y, s.y);
        ms.z = fmaxf(ms.z, s.z); ms.w = fmaxf(ms.w, s.w);
        me.x = fmaxf(me.x, s.x * e.x); me.y = fmaxf(me.y, s.y * e.y);
        me.z = fmaxf(me.z, s.z * e.z); me.w = fmaxf(me.w, s.w * e.w);
        float sm = s.x + s.y + s.z + s.w;
        for (int o = 32; o; o >>= 1) sm += __shfl_down(sm, o);
        if (lane == 0) psum[w][ci] = sm;
    }
    __syncthreads();
    if (t < 8)
        mean[n * C + cg * 8 + t] =
            (psum[0][t] + psum[1][t] + psum[2][t] + psum[3][t]) * (1.0f / HW);
    size_t pb = ((size_t)n * 32 + cg) * HW + p4;
    *(float4*)(pms + pb) = ms;
    *(float4*)(pme + pb) = me;
}

// ---------- pool pass 2 (+ ch_att fold) ----------
__global__ void __launch_bounds__(256) k_pool2(const float* pms, const float* pme,
        float* a2, float* bq, const float* ws2, const float* bs2,
        const float* ws3, const float* bs3,
        const float* mean, const float* Wmlp, const float* bmlp, float* chat) {
    int n = blockIdx.x, t = threadIdx.x;
    int p4 = t << 2;
    float4 ms = make_float4(-3e38f, -3e38f, -3e38f, -3e38f);
    float4 me = ms;
    for (int cg = 0; cg < 32; cg++) {
        size_t pb = ((size_t)n * 32 + cg) * HW + p4;
        float4 a = *(const float4*)(pms + pb);
        float4 b = *(const float4*)(pme + pb);
        ms.x = fmaxf(ms.x, a.x); ms.y = fmaxf(ms.y, a.y);
        ms.z = fmaxf(ms.z, a.z); ms.w = fmaxf(ms.w, a.w);
        me.x = fmaxf(me.x, b.x); me.y = fmaxf(me.y, b.y);
        me.z = fmaxf(me.z, b.z); me.w = fmaxf(me.w, b.w);
    }
    float w3 = ws3[0], b3 = bs3[0], w2 = ws2[0], b2 = bs2[0];
    float4 av, bv;
    av.x = (me.x * w3 + b3) * LOG2E; av.y = (me.y * w3 + b3) * LOG2E;
    av.z = (me.z * w3 + b3) * LOG2E; av.w = (me.w * w3 + b3) * LOG2E;
    bv.x = ms.x * w2 + b2; bv.y = ms.y * w2 + b2;
    bv.z = ms.z * w2 + b2; bv.w = ms.w * w2 + b2;
    *(float4*)(a2 + (size_t)n * HW + p4) = av;
    *(float4*)(bq + (size_t)n * HW + p4) = bv;
    if (t < S) {            // ch_att fold (reads k_pool1's mean)
        float acc = 0.f;
        const float* wr = Wmlp + (size_t)t * C;
        for (int c = 0; c < C; c++) acc += mean[n * C + c] * wr[c];
        chat[n * S + t] = fmaxf(acc + bmlp[t], 0.f);
    }
}

// ---------- projections: seg_s (rows 0..63) & seg_c (rows 64..127) ----------
__global__ void __launch_bounds__(512) k_proj(const f16* segf, const f16* Wf,
        const float* bs1, const float* bs11, f16* segs16, f16* segc) {
    int n = blockIdx.x;                 // n-major grid (32, 16)
    int q0 = blockIdx.y * 64;
    __shared__ f16 sT[64][260];   // [q][c], stride 260
    const f16* sb = segf + (size_t)n * C * HW + q0;
    int tid = threadIdx.x;
    for (int idx = tid; idx < 2048; idx += 512) {
        int c = idx >> 3, q8 = (idx & 7) << 3;
        f16x8 v = *(const f16x8*)(sb + (size_t)c * HW + q8);
        for (int j = 0; j < 8; j++) sT[q8 + j][c] = v[j];
    }
    __syncthreads();
    int lane = tid & 63, wv = tid >> 6;
    int lm = lane & 15, lg = lane >> 4;
    f32x4 acc[4] = {};
    for (int ck = 0; ck < 8; ck++) {
        int c0 = ck * 32;
        f16x8 a0 = *(const f16x8*)(Wf + (size_t)(wv * 16 + lm) * C + c0 + lg * 8);
        for (int j = 0; j < 4; j++) {
            f16x8 b = lds_ld8(&sT[j * 16 + lm][c0 + lg * 8]);
            acc[j] = MFMA(a0, b, acc[j]);
        }
    }
    for (int rr = 0; rr < 4; rr++) {
        int row = wv * 16 + lg * 4 + rr;
        float bias = (row < S) ? bs1[row] : bs11[row - S];
        for (int j = 0; j < 4; j++) {
            int q = q0 + j * 16 + lm;
            float v = acc[j][rr] + bias;
            if (row < S) segs16[((size_t)n * S + row) * HW + q] = (f16)v;
            else         segc[((size_t)n * S + (row - S)) * HW + q] = (f16)v;
        }
    }
}

// ---------- dp2[p], e[q], partial dp2 max/min; grid (32, 8) ----------
__global__ void __launch_bounds__(256) k_dp(const f16* segs16, const float* chat,
        float* dp2, float* e_, float* dpmm2) {
    int n = blockIdx.x, g = blockIdx.y, t = threadIdx.x;
    __shared__ float cA[S];
    __shared__ float rmx[2], rmn[2];
    if (t < S) cA[t] = chat[n * S + t];
    __syncthreads();
    const f16* ss = segs16 + (size_t)n * S * HW;
    if (t < 128) {
        int p = g * 128 + t;
        const f16* bb = ss + (size_t)(p >> 4) * HW + ((p & 15) << 6);
        float acc = 0.f;
        for (int tt = 0; tt < S; tt += 8) {
            f16x8 v = *(const f16x8*)(bb + tt);
            for (int j = 0; j < 8; j++) acc += (float)v[j] * cA[tt + j];
        }
        float d2 = acc * LOG2E;
        dp2[(size_t)n * HW + p] = d2;
        float mx = d2, mn = d2;
        for (int o = 32; o; o >>= 1) {
            mx = fmaxf(mx, __shfl_down(mx, o));
            mn = fminf(mn, __shfl_down(mn, o));
        }
        if ((t & 63) == 0) { rmx[t >> 6] = mx; rmn[t >> 6] = mn; }
    } else {
        int q = g * 128 + (t - 128);
        float acc = 0.f;
        for (int tt = 0; tt < S; tt++) acc += cA[tt] * (float)ss[(size_t)tt * HW + q];
        e_[(size_t)n * HW + q] = acc;
    }
    __syncthreads();
    if (t == 0) {
        dpmm2[(n * 8 + g) * 2]     = fmaxf(rmx[0], rmx[1]);
        dpmm2[(n * 8 + g) * 2 + 1] = fminf(rmn[0], rmn[1]);
    }
}

// ---------- sim_c softmax stats (Mc, 1/Zc); grid (32,16), 4 thr/q ----------
__global__ void __launch_bounds__(256) k_zc(const float* dp2, const float* e_,
        const float* dpmm2, float* Mc2, float* iZc) {
    int n = blockIdx.x, g = blockIdx.y, t = threadIdx.x;
    __shared__ float d[HW];
    for (int i = t; i < HW; i += 256) d[i] = dp2[(size_t)n * HW + i];
    float mx = -3e38f, mn = 3e38f;
    for (int j = 0; j < 8; j++) {
        mx = fmaxf(mx, dpmm2[(n * 8 + j) * 2]);
        mn = fminf(mn, dpmm2[(n * 8 + j) * 2 + 1]);
    }
    __syncthreads();
    int q = g * 64 + (t >> 2);
    float eq = e_[(size_t)n * HW + q];
    float m = (eq > 0.f) ? eq * mx : eq * mn;
    float z = 0.f;
    for (int p = (t & 3); p < HW; p += 4) z += EXP2(d[p] * eq - m);
    z += __shfl_xor(z, 1);
    z += __shfl_xor(z, 2);
    if ((t & 3) == 0) {
        Mc2[(size_t)n * HW + q] = m;
        iZc[(size_t)n * HW + q] = 1.f / z;
    }
}

// ---------- sim_s softmax stats (Ms, 1/Ls); p 4-way split; grid (32, 32) ----------
__global__ void __launch_bounds__(512) k_sstats(const f16* segc, const float* a2,
        const float* bq, float* Ms2, float* iZs) {
    int n = blockIdx.x, q0 = blockIdx.y * 32;
    __shared__ f16 bT[32][68];
    __shared__ float a2s[HW];
    __shared__ float mred[32][4], lred[32][4];
    const f16* cb = segc + (size_t)n * S * HW;
    int tid = threadIdx.x;
    if (tid < 256) {
        int th = tid >> 2, q8 = (tid & 3) << 3;
        f16x8 v = *(const f16x8*)(cb + (size_t)th * HW + q0 + q8);
        for (int j = 0; j < 8; j++) bT[q8 + j][th] = v[j];
    }
    for (int i = tid; i < HW; i += 512) a2s[i] = a2[(size_t)n * HW + i];
    __syncthreads();
    int w = tid >> 6, lane = tid & 63, lm = lane & 15, lg = lane >> 4;
    int qg = w >> 2, ph = w & 3;   // 2 q-groups x 4 p-quarters
    f16x8 b0 = lds_ld8(&bT[qg * 16 + lm][lg * 8]);
    f16x8 b1 = lds_ld8(&bT[qg * 16 + lm][32 + lg * 8]);
    float bqv = bq[(size_t)n * HW + q0 + qg * 16 + lm];
    float m = -3e38f, l = 0.f;
    for (int it = 0; it < 8; it++) {
        int pb = ph * 256 + it * 32;
        f16x8 a0 = *(const f16x8*)(cb + (size_t)(pb + lm) * S + lg * 8);
        f16x8 a1 = *(const f16x8*)(cb + (size_t)(pb + lm) * S + 32 + lg * 8);
        f16x8 c0 = *(const f16x8*)(cb + (size_t)(pb + 16 + lm) * S + lg * 8);
        f16x8 c1 = *(const f16x8*)(cb + (size_t)(pb + 16 + lm) * S + 32 + lg * 8);
        f32x4 sgA = {}, sgB = {};
        sgA = MFMA(a0, b0, sgA); sgA = MFMA(a1, b1, sgA);
        sgB = MFMA(c0, b0, sgB); sgB = MFMA(c1, b1, sgB);
        float sc[8];
        float fm = -3e38f;
        for (int rr = 0; rr < 4; rr++) {
            float avA = a2s[pb + lg * 4 + rr];
            float avB = a2s[pb + 16 + lg * 4 + rr];
            sc[rr]     = avA * bqv * sgA[rr];
            sc[rr + 4] = avB * bqv * sgB[rr];
            fm = fmaxf(fm, fmaxf(sc[rr], sc[rr + 4]));
        }
        fm = fmaxf(fm, __shfl_xor(fm, 16));
        fm = fmaxf(fm, __shfl_xor(fm, 32));
        float fl = 0.f;
        for (int rr = 0; rr < 8; rr++) fl += EXP2(sc[rr] - fm);
        fl += __shfl_xor(fl, 16);
        fl += __shfl_xor(fl, 32);
        float nm = fmaxf(m, fm);
        l = l * EXP2(m - nm) + fl * EXP2(fm - nm);
        m = nm;
    }
    if (lg == 0) { mred[qg * 16 + lm][ph] = m; lred[qg * 16 + lm][ph] = l; }
    __syncthreads();
    if (tid < 32) {
        float M = fmaxf(fmaxf(mred[tid][0], mred[tid][1]),
                        fmaxf(mred[tid][2], mred[tid][3]));
        float L = lred[tid][0] * EXP2(mred[tid][0] - M)
                + lred[tid][1] * EXP2(mred[tid][1] - M)
                + lred[tid][2] * EXP2(mred[tid][2] - M)
                + lred[tid][3] * EXP2(mred[tid][3] - M);
        Ms2[(size_t)n * HW + q0 + tid] = M;
        iZs[(size_t)n * HW + q0 + tid] = 1.f / L;
    }
}

// ---------- fused: sigma -> weights -> seg_sim; q-tile 32, 4 blocks/CU ----------
// M-subtraction kept IN the exponent: spatial logits reach |.|~hundreds in
// log2 units; 2^(-M) underflows / 2^(logit) overflows if folded (round-6 bug).
__global__ void __launch_bounds__(512, 8) k_fused(const f16* segf, const f16* segc,
        const float* dp2, const float* e_, const float* a2, const float* bq,
        const float* Mc2, const float* iZc, const float* Ms2, const float* iZs,
        f16* simT) {
    int n = blockIdx.x, q0 = blockIdx.y * 32;   // grid (32, 32)
    __shared__ f16 bT[32][68];        // segc^T tile [q][t]
    __shared__ f16 wT[2][32][132];    // dbuf weight tile [q][p_local]
    __shared__ float dp2s[HW], a2s[HW];
    const f16* cb = segc + (size_t)n * S * HW;
    const f16* sb = segf + (size_t)n * C * HW;
    int tid = threadIdx.x;
    if (tid < 256) {
        int th = tid >> 2, q8 = (tid & 3) << 3;
        f16x8 v = *(const f16x8*)(cb + (size_t)th * HW + q0 + q8);
        for (int j = 0; j < 8; j++) bT[q8 + j][th] = v[j];
    }
    for (int i = tid; i < HW; i += 512) {
        dp2s[i] = dp2[(size_t)n * HW + i];
        a2s[i]  = a2[(size_t)n * HW + i];
    }
    __syncthreads();
    int w = tid >> 6, lane = tid & 63, lm = lane & 15, lg = lane >> 4;
    float ev[2], bqv[2], mcv[2], izcv[2], msv[2], izsv[2];
    for (int j = 0; j < 2; j++) {
        size_t gq = (size_t)n * HW + q0 + j * 16 + lm;
        ev[j] = e_[gq]; bqv[j] = bq[gq];
        mcv[j] = Mc2[gq]; izcv[j] = iZc[gq];
        msv[j] = Ms2[gq]; izsv[j] = iZs[gq];
    }
    f32x4 acc[2][2] = {};   // 32 c-rows x 32 q per wave
    for (int chk = 0; chk <= 8; chk++) {
        if (chk < 8) {
            // stage 1: chunk chk (128 p) -> wT[chk&1]; wave w: p_local w*16..+16
            int p0 = chk * 128;
            int prow = p0 + w * 16 + lm;
            f16x8 sa0 = *(const f16x8*)(cb + (size_t)prow * S + lg * 8);
            f16x8 sa1 = *(const f16x8*)(cb + (size_t)prow * S + 32 + lg * 8);
            f32x4 d2r = *(const f32x4*)&dp2s[p0 + w * 16 + lg * 4];
            f32x4 avr = *(const f32x4*)&a2s[p0 + w * 16 + lg * 4];
            for (int j = 0; j < 2; j++) {
                f16x8 bb0 = lds_ld8(&bT[j * 16 + lm][lg * 8]);
                f16x8 bb1 = lds_ld8(&bT[j * 16 + lm][32 + lg * 8]);
                f32x4 sg = {};
                sg = MFMA(sa0, bb0, sg);
                sg = MFMA(sa1, bb1, sg);
                float wgt[4];
                for (int rr = 0; rr < 4; rr++) {
                    float wc  = EXP2(d2r[rr] * ev[j] - mcv[j]) * izcv[j];
                    float wsv = EXP2(avr[rr] * bqv[j] * sg[rr] - msv[j]) * izsv[j];
                    wgt[rr] = wc + wsv;
                }
                int ql = j * 16 + lm;
                int pp = w * 16 + lg * 4;
                union { f16 h[2]; unsigned u; } c0u, c1u;
                c0u.h[0] = (f16)wgt[0]; c0u.h[1] = (f16)wgt[1];
                c1u.h[0] = (f16)wgt[2]; c1u.h[1] = (f16)wgt[3];
                *(unsigned*)&wT[chk & 1][ql][pp]     = c0u.u;
                *(unsigned*)&wT[chk & 1][ql][pp + 2] = c1u.u;
            }
        }
        if (chk > 0) {
            // stage 2: chunk chk-1 from wT[(chk-1)&1]; K = 128
            int p0 = (chk - 1) * 128;
            int cur = (chk - 1) & 1;
            for (int ks = 0; ks < 4; ks++) {
                f16x8 af0 = *(const f16x8*)(sb + (size_t)(w * 32 + lm) * HW + p0 + ks * 32 + lg * 8);
                f16x8 af1 = *(const f16x8*)(sb + (size_t)(w * 32 + 16 + lm) * HW + p0 + ks * 32 + lg * 8);
                for (int qf = 0; qf < 2; qf++) {
                    f16x8 bb = lds_ld8(&wT[cur][qf * 16 + lm][ks * 32 + lg * 8]);
                    acc[0][qf] = MFMA(af0, bb, acc[0][qf]);
                    acc[1][qf] = MFMA(af1, bb, acc[1][qf]);
                }
            }
        }
        __syncthreads();
    }
    for (int cf = 0; cf < 2; cf++)
        for (int qf = 0; qf < 2; qf++) {
            int crow = w * 32 + cf * 16 + lg * 4;
            size_t qrow = (size_t)n * HW + q0 + qf * 16 + lm;
            union { f16 h[2]; unsigned u; } c0u, c1u;
            c0u.h[0] = (f16)acc[cf][qf][0]; c0u.h[1] = (f16)acc[cf][qf][1];
            c1u.h[0] = (f16)acc[cf][qf][2]; c1u.h[1] = (f16)acc[cf][qf][3];
            *(unsigned*)(simT + qrow * C + crow)     = c0u.u;
            *(unsigned*)(simT + qrow * C + crow + 2) = c1u.u;
        }
}

// ---------- out = relu(Wg @ seg_sim + bg) + 2*seg_ori (f16 seg copy) ----------
__global__ void __launch_bounds__(512) k_out(const f16* Wgf, const f16* simT,
        const float* bg, const f16* segf, float* out) {
    int n = blockIdx.x, q0 = blockIdx.y * 64;   // n-major grid (32, 16)
    int tid = threadIdx.x, w = tid >> 6, lane = tid & 63, lm = lane & 15, lg = lane >> 4;
    int ow = (w & 3) * 64, qh = (w >> 2) * 32;
    f32x4 acc[4][2] = {};
    for (int ck = 0; ck < 8; ck++) {
        int c0 = ck * 32;
        f16x8 af[4], bf[2];
        for (int of = 0; of < 4; of++)
            af[of] = *(const f16x8*)(Wgf + (size_t)(ow + of * 16 + lm) * C + c0 + lg * 8);
        for (int qf = 0; qf < 2; qf++)
            bf[qf] = *(const f16x8*)(simT + ((size_t)n * HW + q0 + qh + qf * 16 + lm) * C + c0 + lg * 8);
        for (int of = 0; of < 4; of++)
            for (int qf = 0; qf < 2; qf++)
                acc[of][qf] = MFMA(af[of], bf[qf], acc[of][qf]);
    }
    for (int of = 0; of < 4; of++)
        for (int rr = 0; rr < 4; rr++) {
            int o = ow + of * 16 + lg * 4 + rr;
            float bgv = bg[o];
            for (int qf = 0; qf < 2; qf++) {
                int q = q0 + qh + qf * 16 + lm;
                size_t ix = ((size_t)n * C + o) * HW + q;
                out[ix] = fmaxf(acc[of][qf][rr] + bgv, 0.f) + 2.f * (float)segf[ix];
            }
        }
}

extern "C" void kernel_launch(void* const* d_in, const int* in_sizes, int n_in,
                              void* d_out, int out_size, void* d_ws, size_t ws_size,
                              hipStream_t stream) {
    const float* seg  = (const float*)d_in[0];
    const float* edge = (const float*)d_in[1];
    const float* Ws1  = (const float*)d_in[2];
    const float* bs1  = (const float*)d_in[3];
    const float* Ws11 = (const float*)d_in[4];
    const float* bs11 = (const float*)d_in[5];
    const float* Wmlp = (const float*)d_in[6];
    const float* bmlp = (const float*)d_in[7];
    const float* ws2  = (const float*)d_in[8];
    const float* bs2  = (const float*)d_in[9];
    const float* ws3  = (const float*)d_in[10];
    const float* bs3  = (const float*)d_in[11];
    const float* Wg   = (const float*)d_in[12];
    const float* bg   = (const float*)d_in[13];
    float* out = (float*)d_out;
    char* wsb = (char*)d_ws;

    f16*   segf   = (f16*)(wsb);                   // 16777216 B
    f16*   segc   = (f16*)(wsb + 16777216);        //  4194304 B
    f16*   segs16 = (f16*)(wsb + 20971520);        //  4194304 B
    f16*   simT   = (f16*)(wsb + 25165824);        // 16777216 B
    // pms/pme overlay the simT region (dead until k_fused writes it)
    float* pms    = (float*)(wsb + 25165824);             // 4 MB
    float* pme    = (float*)(wsb + 29360128);             // 4 MB
    f16*   Wf     = (f16*)(wsb + 41943040);        //    65536 B
    f16*   Wgf    = (f16*)(wsb + 42008576);        //   131072 B
    float* mean   = (float*)(wsb + 42139648);      //    32768 B
    float* chat   = (float*)(wsb + 42172416);      //     8192 B
    float* dp2    = (float*)(wsb + 42180608);      //   131072 B
    float* e_     = (float*)(wsb + 42311680);
    float* a2     = (float*)(wsb + 42442752);
    float* bq     = (float*)(wsb + 42573824);
    float* Mc2    = (float*)(wsb + 42704896);
    float* iZc    = (float*)(wsb + 42835968);
    float* Ms2    = (float*)(wsb + 42967040);
    float* iZs    = (float*)(wsb + 43098112);
    float* dpmm2  = (float*)(wsb + 43229184);      //     2048 B

    k_pool1<<<dim3(32, 32), 256, 0, stream>>>(seg, edge, segf, pms, pme, mean,
                                              Ws1, Ws11, Wg, Wf, Wgf);
    k_pool2<<<32, 256, 0, stream>>>(pms, pme, a2, bq, ws2, bs2, ws3, bs3,
                                    mean, Wmlp, bmlp, chat);
    k_proj<<<dim3(32, 16), 512, 0, stream>>>(segf, Wf, bs1, bs11, segs16, segc);
    k_dp<<<dim3(32, 8), 256, 0, stream>>>(segs16, chat, dp2, e_, dpmm2);
    k_zc<<<dim3(32, 16), 256, 0, stream>>>(dp2, e_, dpmm2, Mc2, iZc);
    k_sstats<<<dim3(32, 32), 512, 0, stream>>>(segc, a2, bq, Ms2, iZs);
    k_fused<<<dim3(32, 32), 512, 0, stream>>>(segf, segc, dp2, e_, a2, bq,
                                              Mc2, iZc, Ms2, iZs, simT);
    k_out<<<dim3(32, 16), 512, 0, stream>>>(Wgf, simT, bg, segf, out);
}

// Round 8
// 313.984 us; speedup vs baseline: 1.1003x; 1.1003x over previous
//
#include <hip/hip_runtime.h>

#define N 32
#define C 256
#define HW 1024
#define S 64
#define LOG2E 1.4426950408889634f

typedef _Float16 f16;
typedef _Float16 f16x4 __attribute__((ext_vector_type(4)));
typedef _Float16 f16x8 __attribute__((ext_vector_type(8)));
typedef float f32x4 __attribute__((ext_vector_type(4)));

#define MFMA(a, b, c) __builtin_amdgcn_mfma_f32_16x16x32_f16(a, b, c, 0, 0, 0)
#define EXP2(x) exp2f(x)

// 8B-aligned LDS f16x8 load (two ds_read_b64)
__device__ inline f16x8 lds_ld8(const f16* p) {
    f16x4 a = *(const f16x4*)p;
    f16x4 b = *(const f16x4*)(p + 4);
    f16x8 r;
    r[0] = a[0]; r[1] = a[1]; r[2] = a[2]; r[3] = a[3];
    r[4] = b[0]; r[5] = b[1]; r[6] = b[2]; r[7] = b[3];
    return r;
}

// ---------- pool pass 1 (+ weight conversion fold): float4 stream ----------
__global__ void __launch_bounds__(256) k_pool1(const float* seg, const float* edge,
        f16* segf, float* pms, float* pme, float* mean,
        const float* Ws1, const float* Ws11, const float* Wg, f16* Wf, f16* Wgf) {
    int n = blockIdx.x, cg = blockIdx.y;          // grid (32, 32), 8 c per block
    int t = threadIdx.x, w = t >> 6, lane = t & 63;
    int flat = n * 32 + cg;
    if (flat < 256) {                              // weight conversion fold
        int i = flat * 256 + t;
        if (i < S * C) { Wf[i] = (f16)Ws1[i]; Wf[S * C + i] = (f16)Ws11[i]; }
        Wgf[i] = (f16)Wg[i];
    }
    int p4 = (lane << 2) + (w << 8);
    size_t base = (size_t)n * C * HW;
    float4 ms = make_float4(-3e38f, -3e38f, -3e38f, -3e38f);
    float4 me = ms;
    __shared__ float psum[4][8];
    for (int ci = 0; ci < 8; ci++) {
        int c = cg * 8 + ci;
        size_t off = base + (size_t)c * HW + p4;
        float4 s = *(const float4*)(seg + off);
        float4 e = *(const float4*)(edge + off);
        union { f16 h[4]; unsigned long long u; } pk;
        pk.h[0] = (f16)s.x; pk.h[1] = (f16)s.y; pk.h[2] = (f16)s.z; pk.h[3] = (f16)s.w;
        *(unsigned long long*)(segf + off) = pk.u;
        ms.x = fmaxf(ms.x, s.x); ms.y = fmaxf(ms.y, s.y);
        ms.z = fmaxf(ms.z, s.z); ms.w = fmaxf(ms.w, s.w);
        me.x = fmaxf(me.x, s.x * e.x); me.y = fmaxf(me.y, s.y * e.y);
        me.z = fmaxf(me.z, s.z * e.z); me.w = fmaxf(me.w, s.w * e.w);
        float sm = s.x + s.y + s.z + s.w;
        for (int o = 32; o; o >>= 1) sm += __shfl_down(sm, o);
        if (lane == 0) psum[w][ci] = sm;
    }
    __syncthreads();
    if (t < 8)
        mean[n * C + cg * 8 + t] =
            (psum[0][t] + psum[1][t] + psum[2][t] + psum[3][t]) * (1.0f / HW);
    size_t pb = ((size_t)n * 32 + cg) * HW + p4;
    *(float4*)(pms + pb) = ms;
    *(float4*)(pme + pb) = me;
}

// ---------- pool pass 2 (+ ch_att fold) ----------
__global__ void __launch_bounds__(256) k_pool2(const float* pms, const float* pme,
        float* a2, float* bq, const float* ws2, const float* bs2,
        const float* ws3, const float* bs3,
        const float* mean, const float* Wmlp, const float* bmlp, float* chat) {
    int n = blockIdx.x, t = threadIdx.x;
    int p4 = t << 2;
    float4 ms = make_float4(-3e38f, -3e38f, -3e38f, -3e38f);
    float4 me = ms;
    for (int cg = 0; cg < 32; cg++) {
        size_t pb = ((size_t)n * 32 + cg) * HW + p4;
        float4 a = *(const float4*)(pms + pb);
        float4 b = *(const float4*)(pme + pb);
        ms.x = fmaxf(ms.x, a.x); ms.y = fmaxf(ms.y, a.y);
        ms.z = fmaxf(ms.z, a.z); ms.w = fmaxf(ms.w, a.w);
        me.x = fmaxf(me.x, b.x); me.y = fmaxf(me.y, b.y);
        me.z = fmaxf(me.z, b.z); me.w = fmaxf(me.w, b.w);
    }
    float w3 = ws3[0], b3 = bs3[0], w2 = ws2[0], b2 = bs2[0];
    float4 av, bv;
    av.x = (me.x * w3 + b3) * LOG2E; av.y = (me.y * w3 + b3) * LOG2E;
    av.z = (me.z * w3 + b3) * LOG2E; av.w = (me.w * w3 + b3) * LOG2E;
    bv.x = ms.x * w2 + b2; bv.y = ms.y * w2 + b2;
    bv.z = ms.z * w2 + b2; bv.w = ms.w * w2 + b2;
    *(float4*)(a2 + (size_t)n * HW + p4) = av;
    *(float4*)(bq + (size_t)n * HW + p4) = bv;
    if (t < S) {            // ch_att fold (reads k_pool1's mean)
        float acc = 0.f;
        const float* wr = Wmlp + (size_t)t * C;
        for (int c = 0; c < C; c++) acc += mean[n * C + c] * wr[c];
        chat[n * S + t] = fmaxf(acc + bmlp[t], 0.f);
    }
}

// ---------- projections: seg_s (rows 0..63) & seg_c (rows 64..127) ----------
__global__ void __launch_bounds__(512) k_proj(const f16* segf, const f16* Wf,
        const float* bs1, const float* bs11, f16* segs16, f16* segc) {
    int n = blockIdx.x;                 // n-major grid (32, 16)
    int q0 = blockIdx.y * 64;
    __shared__ f16 sT[64][260];   // [q][c], stride 260
    const f16* sb = segf + (size_t)n * C * HW + q0;
    int tid = threadIdx.x;
    for (int idx = tid; idx < 2048; idx += 512) {
        int c = idx >> 3, q8 = (idx & 7) << 3;
        f16x8 v = *(const f16x8*)(sb + (size_t)c * HW + q8);
        for (int j = 0; j < 8; j++) sT[q8 + j][c] = v[j];
    }
    __syncthreads();
    int lane = tid & 63, wv = tid >> 6;
    int lm = lane & 15, lg = lane >> 4;
    f32x4 acc[4] = {};
    for (int ck = 0; ck < 8; ck++) {
        int c0 = ck * 32;
        f16x8 a0 = *(const f16x8*)(Wf + (size_t)(wv * 16 + lm) * C + c0 + lg * 8);
        for (int j = 0; j < 4; j++) {
            f16x8 b = lds_ld8(&sT[j * 16 + lm][c0 + lg * 8]);
            acc[j] = MFMA(a0, b, acc[j]);
        }
    }
    for (int rr = 0; rr < 4; rr++) {
        int row = wv * 16 + lg * 4 + rr;
        float bias = (row < S) ? bs1[row] : bs11[row - S];
        for (int j = 0; j < 4; j++) {
            int q = q0 + j * 16 + lm;
            float v = acc[j][rr] + bias;
            if (row < S) segs16[((size_t)n * S + row) * HW + q] = (f16)v;
            else         segc[((size_t)n * S + (row - S)) * HW + q] = (f16)v;
        }
    }
}

// ---------- dp2[p], e[q], partial dp2 max/min; grid (32, 8) ----------
__global__ void __launch_bounds__(256) k_dp(const f16* segs16, const float* chat,
        float* dp2, float* e_, float* dpmm2) {
    int n = blockIdx.x, g = blockIdx.y, t = threadIdx.x;
    __shared__ float cA[S];
    __shared__ float rmx[2], rmn[2];
    if (t < S) cA[t] = chat[n * S + t];
    __syncthreads();
    const f16* ss = segs16 + (size_t)n * S * HW;
    if (t < 128) {
        int p = g * 128 + t;
        const f16* bb = ss + (size_t)(p >> 4) * HW + ((p & 15) << 6);
        float acc = 0.f;
        for (int tt = 0; tt < S; tt += 8) {
            f16x8 v = *(const f16x8*)(bb + tt);
            for (int j = 0; j < 8; j++) acc += (float)v[j] * cA[tt + j];
        }
        float d2 = acc * LOG2E;
        dp2[(size_t)n * HW + p] = d2;
        float mx = d2, mn = d2;
        for (int o = 32; o; o >>= 1) {
            mx = fmaxf(mx, __shfl_down(mx, o));
            mn = fminf(mn, __shfl_down(mn, o));
        }
        if ((t & 63) == 0) { rmx[t >> 6] = mx; rmn[t >> 6] = mn; }
    } else {
        int q = g * 128 + (t - 128);
        float acc = 0.f;
        for (int tt = 0; tt < S; tt++) acc += cA[tt] * (float)ss[(size_t)tt * HW + q];
        e_[(size_t)n * HW + q] = acc;
    }
    __syncthreads();
    if (t == 0) {
        dpmm2[(n * 8 + g) * 2]     = fmaxf(rmx[0], rmx[1]);
        dpmm2[(n * 8 + g) * 2 + 1] = fminf(rmn[0], rmn[1]);
    }
}

// ---------- sim_c softmax stats (Mc, 1/Zc); grid (32,32), 8 thr/q ----------
__global__ void __launch_bounds__(256) k_zc(const float* dp2, const float* e_,
        const float* dpmm2, float* Mc2, float* iZc) {
    int n = blockIdx.x, g = blockIdx.y, t = threadIdx.x;
    __shared__ float d[HW];
    for (int i = t; i < HW; i += 256) d[i] = dp2[(size_t)n * HW + i];
    float mx = -3e38f, mn = 3e38f;
    for (int j = 0; j < 8; j++) {
        mx = fmaxf(mx, dpmm2[(n * 8 + j) * 2]);
        mn = fminf(mn, dpmm2[(n * 8 + j) * 2 + 1]);
    }
    __syncthreads();
    int q = g * 32 + (t >> 3);      // 32 q per block
    int pi = t & 7;
    float eq = e_[(size_t)n * HW + q];
    float m = (eq > 0.f) ? eq * mx : eq * mn;
    float z = 0.f;
    // p = pi + 8*j : interleaved stripes, broadcast-friendly LDS banks
    for (int j = 0; j < 128; j++) z += EXP2(d[pi + 8 * j] * eq - m);
    z += __shfl_xor(z, 1);
    z += __shfl_xor(z, 2);
    z += __shfl_xor(z, 4);
    if (pi == 0) {
        Mc2[(size_t)n * HW + q] = m;
        iZc[(size_t)n * HW + q] = 1.f / z;
    }
}

// ---------- sim_s softmax stats (Ms, 1/Ls); p 4-way split; grid (32, 32) ----------
__global__ void __launch_bounds__(512) k_sstats(const f16* segc, const float* a2,
        const float* bq, float* Ms2, float* iZs) {
    int n = blockIdx.x, q0 = blockIdx.y * 32;
    __shared__ f16 bT[32][68];
    __shared__ float a2s[HW];
    __shared__ float mred[32][4], lred[32][4];
    const f16* cb = segc + (size_t)n * S * HW;
    int tid = threadIdx.x;
    if (tid < 256) {
        int th = tid >> 2, q8 = (tid & 3) << 3;
        f16x8 v = *(const f16x8*)(cb + (size_t)th * HW + q0 + q8);
        for (int j = 0; j < 8; j++) bT[q8 + j][th] = v[j];
    }
    for (int i = tid; i < HW; i += 512) a2s[i] = a2[(size_t)n * HW + i];
    __syncthreads();
    int w = tid >> 6, lane = tid & 63, lm = lane & 15, lg = lane >> 4;
    int qg = w >> 2, ph = w & 3;   // 2 q-groups x 4 p-quarters
    f16x8 b0 = lds_ld8(&bT[qg * 16 + lm][lg * 8]);
    f16x8 b1 = lds_ld8(&bT[qg * 16 + lm][32 + lg * 8]);
    float bqv = bq[(size_t)n * HW + q0 + qg * 16 + lm];
    float m = -3e38f, l = 0.f;
    for (int it = 0; it < 8; it++) {
        int pb = ph * 256 + it * 32;
        f16x8 a0 = *(const f16x8*)(cb + (size_t)(pb + lm) * S + lg * 8);
        f16x8 a1 = *(const f16x8*)(cb + (size_t)(pb + lm) * S + 32 + lg * 8);
        f16x8 c0 = *(const f16x8*)(cb + (size_t)(pb + 16 + lm) * S + lg * 8);
        f16x8 c1 = *(const f16x8*)(cb + (size_t)(pb + 16 + lm) * S + 32 + lg * 8);
        f32x4 sgA = {}, sgB = {};
        sgA = MFMA(a0, b0, sgA); sgA = MFMA(a1, b1, sgA);
        sgB = MFMA(c0, b0, sgB); sgB = MFMA(c1, b1, sgB);
        float sc[8];
        float fm = -3e38f;
        for (int rr = 0; rr < 4; rr++) {
            float avA = a2s[pb + lg * 4 + rr];
            float avB = a2s[pb + 16 + lg * 4 + rr];
            sc[rr]     = avA * bqv * sgA[rr];
            sc[rr + 4] = avB * bqv * sgB[rr];
            fm = fmaxf(fm, fmaxf(sc[rr], sc[rr + 4]));
        }
        fm = fmaxf(fm, __shfl_xor(fm, 16));
        fm = fmaxf(fm, __shfl_xor(fm, 32));
        float fl = 0.f;
        for (int rr = 0; rr < 8; rr++) fl += EXP2(sc[rr] - fm);
        fl += __shfl_xor(fl, 16);
        fl += __shfl_xor(fl, 32);
        float nm = fmaxf(m, fm);
        l = l * EXP2(m - nm) + fl * EXP2(fm - nm);
        m = nm;
    }
    if (lg == 0) { mred[qg * 16 + lm][ph] = m; lred[qg * 16 + lm][ph] = l; }
    __syncthreads();
    if (tid < 32) {
        float M = fmaxf(fmaxf(mred[tid][0], mred[tid][1]),
                        fmaxf(mred[tid][2], mred[tid][3]));
        float L = lred[tid][0] * EXP2(mred[tid][0] - M)
                + lred[tid][1] * EXP2(mred[tid][1] - M)
                + lred[tid][2] * EXP2(mred[tid][2] - M)
                + lred[tid][3] * EXP2(mred[tid][3] - M);
        Ms2[(size_t)n * HW + q0 + tid] = M;
        iZs[(size_t)n * HW + q0 + tid] = 1.f / L;
    }
}

// ---------- fused: sigma -> weights -> seg_sim; q-tile 32 ----------
// launch_bounds (512,6): 84-VGPR budget -> no spill (round-7's (512,8) forced
// VGPR=32 and spilled: WRITE_SIZE 16->108 MB, 2x slower). M-subtraction kept
// IN the exponent (round-6 overflow bug).
__global__ void __launch_bounds__(512, 6) k_fused(const f16* segf, const f16* segc,
        const float* dp2, const float* e_, const float* a2, const float* bq,
        const float* Mc2, const float* iZc, const float* Ms2, const float* iZs,
        f16* simT) {
    int n = blockIdx.x, q0 = blockIdx.y * 32;   // grid (32, 32)
    __shared__ f16 bT[32][68];        // segc^T tile [q][t]
    __shared__ f16 wT[2][32][132];    // dbuf weight tile [q][p_local]
    __shared__ float dp2s[HW], a2s[HW];
    const f16* cb = segc + (size_t)n * S * HW;
    const f16* sb = segf + (size_t)n * C * HW;
    int tid = threadIdx.x;
    if (tid < 256) {
        int th = tid >> 2, q8 = (tid & 3) << 3;
        f16x8 v = *(const f16x8*)(cb + (size_t)th * HW + q0 + q8);
        for (int j = 0; j < 8; j++) bT[q8 + j][th] = v[j];
    }
    for (int i = tid; i < HW; i += 512) {
        dp2s[i] = dp2[(size_t)n * HW + i];
        a2s[i]  = a2[(size_t)n * HW + i];
    }
    __syncthreads();
    int w = tid >> 6, lane = tid & 63, lm = lane & 15, lg = lane >> 4;
    float ev[2], bqv[2], mcv[2], izcv[2], msv[2], izsv[2];
    for (int j = 0; j < 2; j++) {
        size_t gq = (size_t)n * HW + q0 + j * 16 + lm;
        ev[j] = e_[gq]; bqv[j] = bq[gq];
        mcv[j] = Mc2[gq]; izcv[j] = iZc[gq];
        msv[j] = Ms2[gq]; izsv[j] = iZs[gq];
    }
    f32x4 acc[2][2] = {};   // 32 c-rows x 32 q per wave
    for (int chk = 0; chk <= 8; chk++) {
        if (chk < 8) {
            // stage 1: chunk chk (128 p) -> wT[chk&1]; wave w: p_local w*16..+16
            int p0 = chk * 128;
            int prow = p0 + w * 16 + lm;
            f16x8 sa0 = *(const f16x8*)(cb + (size_t)prow * S + lg * 8);
            f16x8 sa1 = *(const f16x8*)(cb + (size_t)prow * S + 32 + lg * 8);
            f32x4 d2r = *(const f32x4*)&dp2s[p0 + w * 16 + lg * 4];
            f32x4 avr = *(const f32x4*)&a2s[p0 + w * 16 + lg * 4];
            for (int j = 0; j < 2; j++) {
                f16x8 bb0 = lds_ld8(&bT[j * 16 + lm][lg * 8]);
                f16x8 bb1 = lds_ld8(&bT[j * 16 + lm][32 + lg * 8]);
                f32x4 sg = {};
                sg = MFMA(sa0, bb0, sg);
                sg = MFMA(sa1, bb1, sg);
                float wgt[4];
                for (int rr = 0; rr < 4; rr++) {
                    float wc  = EXP2(d2r[rr] * ev[j] - mcv[j]) * izcv[j];
                    float wsv = EXP2(avr[rr] * bqv[j] * sg[rr] - msv[j]) * izsv[j];
                    wgt[rr] = wc + wsv;
                }
                int ql = j * 16 + lm;
                int pp = w * 16 + lg * 4;
                union { f16 h[2]; unsigned u; } c0u, c1u;
                c0u.h[0] = (f16)wgt[0]; c0u.h[1] = (f16)wgt[1];
                c1u.h[0] = (f16)wgt[2]; c1u.h[1] = (f16)wgt[3];
                *(unsigned*)&wT[chk & 1][ql][pp]     = c0u.u;
                *(unsigned*)&wT[chk & 1][ql][pp + 2] = c1u.u;
            }
        }
        if (chk > 0) {
            // stage 2: chunk chk-1 from wT[(chk-1)&1]; K = 128
            int p0 = (chk - 1) * 128;
            int cur = (chk - 1) & 1;
            for (int ks = 0; ks < 4; ks++) {
                f16x8 af0 = *(const f16x8*)(sb + (size_t)(w * 32 + lm) * HW + p0 + ks * 32 + lg * 8);
                f16x8 af1 = *(const f16x8*)(sb + (size_t)(w * 32 + 16 + lm) * HW + p0 + ks * 32 + lg * 8);
                for (int qf = 0; qf < 2; qf++) {
                    f16x8 bb = lds_ld8(&wT[cur][qf * 16 + lm][ks * 32 + lg * 8]);
                    acc[0][qf] = MFMA(af0, bb, acc[0][qf]);
                    acc[1][qf] = MFMA(af1, bb, acc[1][qf]);
                }
            }
        }
        __syncthreads();
    }
    for (int cf = 0; cf < 2; cf++)
        for (int qf = 0; qf < 2; qf++) {
            int crow = w * 32 + cf * 16 + lg * 4;
            size_t qrow = (size_t)n * HW + q0 + qf * 16 + lm;
            union { f16 h[2]; unsigned u; } c0u, c1u;
            c0u.h[0] = (f16)acc[cf][qf][0]; c0u.h[1] = (f16)acc[cf][qf][1];
            c1u.h[0] = (f16)acc[cf][qf][2]; c1u.h[1] = (f16)acc[cf][qf][3];
            *(unsigned*)(simT + qrow * C + crow)     = c0u.u;
            *(unsigned*)(simT + qrow * C + crow + 2) = c1u.u;
        }
}

// ---------- out = relu(Wg @ seg_sim + bg) + 2*seg_ori (f16 seg copy) ----------
__global__ void __launch_bounds__(512) k_out(const f16* Wgf, const f16* simT,
        const float* bg, const f16* segf, float* out) {
    int n = blockIdx.x, q0 = blockIdx.y * 64;   // n-major grid (32, 16)
    int tid = threadIdx.x, w = tid >> 6, lane = tid & 63, lm = lane & 15, lg = lane >> 4;
    int ow = (w & 3) * 64, qh = (w >> 2) * 32;
    f32x4 acc[4][2] = {};
    for (int ck = 0; ck < 8; ck++) {
        int c0 = ck * 32;
        f16x8 af[4], bf[2];
        for (int of = 0; of < 4; of++)
            af[of] = *(const f16x8*)(Wgf + (size_t)(ow + of * 16 + lm) * C + c0 + lg * 8);
        for (int qf = 0; qf < 2; qf++)
            bf[qf] = *(const f16x8*)(simT + ((size_t)n * HW + q0 + qh + qf * 16 + lm) * C + c0 + lg * 8);
        for (int of = 0; of < 4; of++)
            for (int qf = 0; qf < 2; qf++)
                acc[of][qf] = MFMA(af[of], bf[qf], acc[of][qf]);
    }
    for (int of = 0; of < 4; of++)
        for (int rr = 0; rr < 4; rr++) {
            int o = ow + of * 16 + lg * 4 + rr;
            float bgv = bg[o];
            for (int qf = 0; qf < 2; qf++) {
                int q = q0 + qh + qf * 16 + lm;
                size_t ix = ((size_t)n * C + o) * HW + q;
                out[ix] = fmaxf(acc[of][qf][rr] + bgv, 0.f) + 2.f * (float)segf[ix];
            }
        }
}

extern "C" void kernel_launch(void* const* d_in, const int* in_sizes, int n_in,
                              void* d_out, int out_size, void* d_ws, size_t ws_size,
                              hipStream_t stream) {
    const float* seg  = (const float*)d_in[0];
    const float* edge = (const float*)d_in[1];
    const float* Ws1  = (const float*)d_in[2];
    const float* bs1  = (const float*)d_in[3];
    const float* Ws11 = (const float*)d_in[4];
    const float* bs11 = (const float*)d_in[5];
    const float* Wmlp = (const float*)d_in[6];
    const float* bmlp = (const float*)d_in[7];
    const float* ws2  = (const float*)d_in[8];
    const float* bs2  = (const float*)d_in[9];
    const float* ws3  = (const float*)d_in[10];
    const float* bs3  = (const float*)d_in[11];
    const float* Wg   = (const float*)d_in[12];
    const float* bg   = (const float*)d_in[13];
    float* out = (float*)d_out;
    char* wsb = (char*)d_ws;

    f16*   segf   = (f16*)(wsb);                   // 16777216 B
    f16*   segc   = (f16*)(wsb + 16777216);        //  4194304 B
    f16*   segs16 = (f16*)(wsb + 20971520);        //  4194304 B
    f16*   simT   = (f16*)(wsb + 25165824);        // 16777216 B
    // pms/pme overlay the simT region (dead until k_fused writes it)
    float* pms    = (float*)(wsb + 25165824);             // 4 MB
    float* pme    = (float*)(wsb + 29360128);             // 4 MB
    f16*   Wf     = (f16*)(wsb + 41943040);        //    65536 B
    f16*   Wgf    = (f16*)(wsb + 42008576);        //   131072 B
    float* mean   = (float*)(wsb + 42139648);      //    32768 B
    float* chat   = (float*)(wsb + 42172416);      //     8192 B
    float* dp2    = (float*)(wsb + 42180608);      //   131072 B
    float* e_     = (float*)(wsb + 42311680);
    float* a2     = (float*)(wsb + 42442752);
    float* bq     = (float*)(wsb + 42573824);
    float* Mc2    = (float*)(wsb + 42704896);
    float* iZc    = (float*)(wsb + 42835968);
    float* Ms2    = (float*)(wsb + 42967040);
    float* iZs    = (float*)(wsb + 43098112);
    float* dpmm2  = (float*)(wsb + 43229184);      //     2048 B

    k_pool1<<<dim3(32, 32), 256, 0, stream>>>(seg, edge, segf, pms, pme, mean,
                                              Ws1, Ws11, Wg, Wf, Wgf);
    k_pool2<<<32, 256, 0, stream>>>(pms, pme, a2, bq, ws2, bs2, ws3, bs3,
                                    mean, Wmlp, bmlp, chat);
    k_proj<<<dim3(32, 16), 512, 0, stream>>>(segf, Wf, bs1, bs11, segs16, segc);
    k_dp<<<dim3(32, 8), 256, 0, stream>>>(segs16, chat, dp2, e_, dpmm2);
    k_zc<<<dim3(32, 32), 256, 0, stream>>>(dp2, e_, dpmm2, Mc2, iZc);
    k_sstats<<<dim3(32, 32), 512, 0, stream>>>(segc, a2, bq, Ms2, iZs);
    k_fused<<<dim3(32, 32), 512, 0, stream>>>(segf, segc, dp2, e_, a2, bq,
                                              Mc2, iZc, Ms2, iZs, simT);
    k_out<<<dim3(32, 16), 512, 0, stream>>>(Wgf, simT, bg, segf, out);
}

// Round 9
// 270.546 us; speedup vs baseline: 1.2769x; 1.1606x over previous
//
#include <hip/hip_runtime.h>

#define N 32
#define C 256
#define HW 1024
#define S 64
#define LOG2E 1.4426950408889634f

typedef _Float16 f16;
typedef _Float16 f16x4 __attribute__((ext_vector_type(4)));
typedef _Float16 f16x8 __attribute__((ext_vector_type(8)));
typedef float f32x4 __attribute__((ext_vector_type(4)));

#define MFMA(a, b, c) __builtin_amdgcn_mfma_f32_16x16x32_f16(a, b, c, 0, 0, 0)
#define EXP2(x) exp2f(x)

// 8B-aligned LDS f16x8 load (two ds_read_b64)
__device__ inline f16x8 lds_ld8(const f16* p) {
    f16x4 a = *(const f16x4*)p;
    f16x4 b = *(const f16x4*)(p + 4);
    f16x8 r;
    r[0] = a[0]; r[1] = a[1]; r[2] = a[2]; r[3] = a[3];
    r[4] = b[0]; r[5] = b[1]; r[6] = b[2]; r[7] = b[3];
    return r;
}

// ---------- pool pass 1 (+ weight conversion fold): float4 stream ----------
__global__ void __launch_bounds__(256) k_pool1(const float* seg, const float* edge,
        f16* segf, float* pms, float* pme, float* mean,
        const float* Ws1, const float* Ws11, const float* Wg, f16* Wf, f16* Wgf) {
    int n = blockIdx.x, cg = blockIdx.y;          // grid (32, 32), 8 c per block
    int t = threadIdx.x, w = t >> 6, lane = t & 63;
    int flat = n * 32 + cg;
    if (flat < 256) {                              // weight conversion fold
        int i = flat * 256 + t;
        if (i < S * C) { Wf[i] = (f16)Ws1[i]; Wf[S * C + i] = (f16)Ws11[i]; }
        Wgf[i] = (f16)Wg[i];
    }
    int p4 = (lane << 2) + (w << 8);
    size_t base = (size_t)n * C * HW;
    float4 ms = make_float4(-3e38f, -3e38f, -3e38f, -3e38f);
    float4 me = ms;
    __shared__ float psum[4][8];
    for (int ci = 0; ci < 8; ci++) {
        int c = cg * 8 + ci;
        size_t off = base + (size_t)c * HW + p4;
        float4 s = *(const float4*)(seg + off);
        float4 e = *(const float4*)(edge + off);
        union { f16 h[4]; unsigned long long u; } pk;
        pk.h[0] = (f16)s.x; pk.h[1] = (f16)s.y; pk.h[2] = (f16)s.z; pk.h[3] = (f16)s.w;
        *(unsigned long long*)(segf + off) = pk.u;
        ms.x = fmaxf(ms.x, s.x); ms.y = fmaxf(ms.y, s.y);
        ms.z = fmaxf(ms.z, s.z); ms.w = fmaxf(ms.w, s.w);
        me.x = fmaxf(me.x, s.x * e.x); me.y = fmaxf(me.y, s.y * e.y);
        me.z = fmaxf(me.z, s.z * e.z); me.w = fmaxf(me.w, s.w * e.w);
        float sm = s.x + s.y + s.z + s.w;
        for (int o = 32; o; o >>= 1) sm += __shfl_down(sm, o);
        if (lane == 0) psum[w][ci] = sm;
    }
    __syncthreads();
    if (t < 8)
        mean[n * C + cg * 8 + t] =
            (psum[0][t] + psum[1][t] + psum[2][t] + psum[3][t]) * (1.0f / HW);
    size_t pb = ((size_t)n * 32 + cg) * HW + p4;
    *(float4*)(pms + pb) = ms;
    *(float4*)(pme + pb) = me;
}

// ---------- pool pass 2 (+ ch_att fold) ----------
__global__ void __launch_bounds__(256) k_pool2(const float* pms, const float* pme,
        float* a2, float* bq, const float* ws2, const float* bs2,
        const float* ws3, const float* bs3,
        const float* mean, const float* Wmlp, const float* bmlp, float* chat) {
    int n = blockIdx.x, t = threadIdx.x;
    int p4 = t << 2;
    float4 ms = make_float4(-3e38f, -3e38f, -3e38f, -3e38f);
    float4 me = ms;
    for (int cg = 0; cg < 32; cg++) {
        size_t pb = ((size_t)n * 32 + cg) * HW + p4;
        float4 a = *(const float4*)(pms + pb);
        float4 b = *(const float4*)(pme + pb);
        ms.x = fmaxf(ms.x, a.x); ms.y = fmaxf(ms.y, a.y);
        ms.z = fmaxf(ms.z, a.z); ms.w = fmaxf(ms.w, a.w);
        me.x = fmaxf(me.x, b.x); me.y = fmaxf(me.y, b.y);
        me.z = fmaxf(me.z, b.z); me.w = fmaxf(me.w, b.w);
    }
    float w3 = ws3[0], b3 = bs3[0], w2 = ws2[0], b2 = bs2[0];
    float4 av, bv;
    av.x = (me.x * w3 + b3) * LOG2E; av.y = (me.y * w3 + b3) * LOG2E;
    av.z = (me.z * w3 + b3) * LOG2E; av.w = (me.w * w3 + b3) * LOG2E;
    bv.x = ms.x * w2 + b2; bv.y = ms.y * w2 + b2;
    bv.z = ms.z * w2 + b2; bv.w = ms.w * w2 + b2;
    *(float4*)(a2 + (size_t)n * HW + p4) = av;
    *(float4*)(bq + (size_t)n * HW + p4) = bv;
    if (t < S) {            // ch_att fold (reads k_pool1's mean)
        float acc = 0.f;
        const float* wr = Wmlp + (size_t)t * C;
        for (int c = 0; c < C; c++) acc += mean[n * C + c] * wr[c];
        chat[n * S + t] = fmaxf(acc + bmlp[t], 0.f);
    }
}

// ---------- projections: seg_s (rows 0..63) & seg_c (rows 64..127) ----------
__global__ void __launch_bounds__(512) k_proj(const f16* segf, const f16* Wf,
        const float* bs1, const float* bs11, f16* segs16, f16* segc) {
    int n = blockIdx.x;                 // n-major grid (32, 16)
    int q0 = blockIdx.y * 64;
    __shared__ f16 sT[64][260];   // [q][c], stride 260
    const f16* sb = segf + (size_t)n * C * HW + q0;
    int tid = threadIdx.x;
    for (int idx = tid; idx < 2048; idx += 512) {
        int c = idx >> 3, q8 = (idx & 7) << 3;
        f16x8 v = *(const f16x8*)(sb + (size_t)c * HW + q8);
        for (int j = 0; j < 8; j++) sT[q8 + j][c] = v[j];
    }
    __syncthreads();
    int lane = tid & 63, wv = tid >> 6;
    int lm = lane & 15, lg = lane >> 4;
    f32x4 acc[4] = {};
    for (int ck = 0; ck < 8; ck++) {
        int c0 = ck * 32;
        f16x8 a0 = *(const f16x8*)(Wf + (size_t)(wv * 16 + lm) * C + c0 + lg * 8);
        for (int j = 0; j < 4; j++) {
            f16x8 b = lds_ld8(&sT[j * 16 + lm][c0 + lg * 8]);
            acc[j] = MFMA(a0, b, acc[j]);
        }
    }
    for (int rr = 0; rr < 4; rr++) {
        int row = wv * 16 + lg * 4 + rr;
        float bias = (row < S) ? bs1[row] : bs11[row - S];
        for (int j = 0; j < 4; j++) {
            int q = q0 + j * 16 + lm;
            float v = acc[j][rr] + bias;
            if (row < S) segs16[((size_t)n * S + row) * HW + q] = (f16)v;
            else         segc[((size_t)n * S + (row - S)) * HW + q] = (f16)v;
        }
    }
}

// ---------- dp2[p], e[q], partial dp2 max/min; grid (32, 8) ----------
__global__ void __launch_bounds__(256) k_dp(const f16* segs16, const float* chat,
        float* dp2, float* e_, float* dpmm2) {
    int n = blockIdx.x, g = blockIdx.y, t = threadIdx.x;
    __shared__ float cA[S];
    __shared__ float rmx[2], rmn[2];
    if (t < S) cA[t] = chat[n * S + t];
    __syncthreads();
    const f16* ss = segs16 + (size_t)n * S * HW;
    if (t < 128) {
        int p = g * 128 + t;
        const f16* bb = ss + (size_t)(p >> 4) * HW + ((p & 15) << 6);
        float acc = 0.f;
        for (int tt = 0; tt < S; tt += 8) {
            f16x8 v = *(const f16x8*)(bb + tt);
            for (int j = 0; j < 8; j++) acc += (float)v[j] * cA[tt + j];
        }
        float d2 = acc * LOG2E;
        dp2[(size_t)n * HW + p] = d2;
        float mx = d2, mn = d2;
        for (int o = 32; o; o >>= 1) {
            mx = fmaxf(mx, __shfl_down(mx, o));
            mn = fminf(mn, __shfl_down(mn, o));
        }
        if ((t & 63) == 0) { rmx[t >> 6] = mx; rmn[t >> 6] = mn; }
    } else {
        int q = g * 128 + (t - 128);
        float acc = 0.f;
        for (int tt = 0; tt < S; tt++) acc += cA[tt] * (float)ss[(size_t)tt * HW + q];
        e_[(size_t)n * HW + q] = acc;
    }
    __syncthreads();
    if (t == 0) {
        dpmm2[(n * 8 + g) * 2]     = fmaxf(rmx[0], rmx[1]);
        dpmm2[(n * 8 + g) * 2 + 1] = fminf(rmn[0], rmn[1]);
    }
}

// ---------- sim_c softmax stats (Mc, 1/Zc); grid (32,32), 8 thr/q ----------
__global__ void __launch_bounds__(256) k_zc(const float* dp2, const float* e_,
        const float* dpmm2, float* Mc2, float* iZc) {
    int n = blockIdx.x, g = blockIdx.y, t = threadIdx.x;
    __shared__ float d[HW];
    for (int i = t; i < HW; i += 256) d[i] = dp2[(size_t)n * HW + i];
    float mx = -3e38f, mn = 3e38f;
    for (int j = 0; j < 8; j++) {
        mx = fmaxf(mx, dpmm2[(n * 8 + j) * 2]);
        mn = fminf(mn, dpmm2[(n * 8 + j) * 2 + 1]);
    }
    __syncthreads();
    int q = g * 32 + (t >> 3);      // 32 q per block
    int pi = t & 7;
    float eq = e_[(size_t)n * HW + q];
    float m = (eq > 0.f) ? eq * mx : eq * mn;
    float z = 0.f;
    for (int j = 0; j < 128; j++) z += EXP2(d[pi + 8 * j] * eq - m);
    z += __shfl_xor(z, 1);
    z += __shfl_xor(z, 2);
    z += __shfl_xor(z, 4);
    if (pi == 0) {
        Mc2[(size_t)n * HW + q] = m;
        iZc[(size_t)n * HW + q] = 1.f / z;
    }
}

// ---------- sim_s softmax stats (Ms, 1/Ls); p 4-way split; grid (32, 32) ----------
__global__ void __launch_bounds__(512) k_sstats(const f16* segc, const float* a2,
        const float* bq, float* Ms2, float* iZs) {
    int n = blockIdx.x, q0 = blockIdx.y * 32;
    __shared__ f16 bT[32][68];
    __shared__ float a2s[HW];
    __shared__ float mred[32][4], lred[32][4];
    const f16* cb = segc + (size_t)n * S * HW;
    int tid = threadIdx.x;
    if (tid < 256) {
        int th = tid >> 2, q8 = (tid & 3) << 3;
        f16x8 v = *(const f16x8*)(cb + (size_t)th * HW + q0 + q8);
        for (int j = 0; j < 8; j++) bT[q8 + j][th] = v[j];
    }
    for (int i = tid; i < HW; i += 512) a2s[i] = a2[(size_t)n * HW + i];
    __syncthreads();
    int w = tid >> 6, lane = tid & 63, lm = lane & 15, lg = lane >> 4;
    int qg = w >> 2, ph = w & 3;   // 2 q-groups x 4 p-quarters
    f16x8 b0 = lds_ld8(&bT[qg * 16 + lm][lg * 8]);
    f16x8 b1 = lds_ld8(&bT[qg * 16 + lm][32 + lg * 8]);
    float bqv = bq[(size_t)n * HW + q0 + qg * 16 + lm];
    float m = -3e38f, l = 0.f;
    for (int it = 0; it < 8; it++) {
        int pb = ph * 256 + it * 32;
        f16x8 a0 = *(const f16x8*)(cb + (size_t)(pb + lm) * S + lg * 8);
        f16x8 a1 = *(const f16x8*)(cb + (size_t)(pb + lm) * S + 32 + lg * 8);
        f16x8 c0 = *(const f16x8*)(cb + (size_t)(pb + 16 + lm) * S + lg * 8);
        f16x8 c1 = *(const f16x8*)(cb + (size_t)(pb + 16 + lm) * S + 32 + lg * 8);
        f32x4 sgA = {}, sgB = {};
        sgA = MFMA(a0, b0, sgA); sgA = MFMA(a1, b1, sgA);
        sgB = MFMA(c0, b0, sgB); sgB = MFMA(c1, b1, sgB);
        float sc[8];
        float fm = -3e38f;
        for (int rr = 0; rr < 4; rr++) {
            float avA = a2s[pb + lg * 4 + rr];
            float avB = a2s[pb + 16 + lg * 4 + rr];
            sc[rr]     = avA * bqv * sgA[rr];
            sc[rr + 4] = avB * bqv * sgB[rr];
            fm = fmaxf(fm, fmaxf(sc[rr], sc[rr + 4]));
        }
        fm = fmaxf(fm, __shfl_xor(fm, 16));
        fm = fmaxf(fm, __shfl_xor(fm, 32));
        float fl = 0.f;
        for (int rr = 0; rr < 8; rr++) fl += EXP2(sc[rr] - fm);
        fl += __shfl_xor(fl, 16);
        fl += __shfl_xor(fl, 32);
        float nm = fmaxf(m, fm);
        l = l * EXP2(m - nm) + fl * EXP2(fm - nm);
        m = nm;
    }
    if (lg == 0) { mred[qg * 16 + lm][ph] = m; lred[qg * 16 + lm][ph] = l; }
    __syncthreads();
    if (tid < 32) {
        float M = fmaxf(fmaxf(mred[tid][0], mred[tid][1]),
                        fmaxf(mred[tid][2], mred[tid][3]));
        float L = lred[tid][0] * EXP2(mred[tid][0] - M)
                + lred[tid][1] * EXP2(mred[tid][1] - M)
                + lred[tid][2] * EXP2(mred[tid][2] - M)
                + lred[tid][3] * EXP2(mred[tid][3] - M);
        Ms2[(size_t)n * HW + q0 + tid] = M;
        iZs[(size_t)n * HW + q0 + tid] = 1.f / L;
    }
}

// ---------- fused: sigma -> weights -> seg_sim; q-tile 64, BK=128, dbuf wT ----------
// ROUND-4 VERSION RESTORED: measured 55.9 us, VGPR 64, no spill.
// (512,8)/(512,6) variants forced VGPR 32/40 -> spill or zero ILP, 2x slower.
// M-subtraction kept IN the exponent (round-6 overflow bug).
__global__ void __launch_bounds__(512, 4) k_fused(const f16* segf, const f16* segc,
        const float* dp2, const float* e_, const float* a2, const float* bq,
        const float* Mc2, const float* iZc, const float* Ms2, const float* iZs,
        f16* simT) {
    int n = blockIdx.x, q0 = blockIdx.y * 64;   // n-major grid (32, 16)
    __shared__ f16 bT[64][68];        // segc^T tile [q][t]
    __shared__ f16 wT[2][64][132];    // dbuf weight tile [q][p_local]
    __shared__ float dp2s[HW], a2s[HW];
    const f16* cb = segc + (size_t)n * S * HW;
    const f16* sb = segf + (size_t)n * C * HW;
    int tid = threadIdx.x;
    for (int idx = tid; idx < 64 * 32; idx += 512) {
        int q = idx & 63, th = (idx >> 6) << 1;
        union { f16 h[2]; unsigned u; } pk;
        pk.h[0] = cb[(size_t)th * HW + q0 + q];
        pk.h[1] = cb[(size_t)(th + 1) * HW + q0 + q];
        *(unsigned*)&bT[q][th] = pk.u;
    }
    for (int i = tid; i < HW; i += 512) {
        dp2s[i] = dp2[(size_t)n * HW + i];
        a2s[i]  = a2[(size_t)n * HW + i];
    }
    __syncthreads();
    int w = tid >> 6, lane = tid & 63, lm = lane & 15, lg = lane >> 4;
    // per-q scalars for the 4 q-frags (stage 1 covers all 64 q per wave)
    float ev[4], bqv[4], mcv[4], izcv[4], msv[4], izsv[4];
    for (int j = 0; j < 4; j++) {
        size_t gq = (size_t)n * HW + q0 + j * 16 + lm;
        ev[j] = e_[gq];  bqv[j] = bq[gq];
        mcv[j] = Mc2[gq]; izcv[j] = iZc[gq];
        msv[j] = Ms2[gq]; izsv[j] = iZs[gq];
    }
    f32x4 acc[2][4] = {};   // 32 c-rows (w*32) x 64 q
    for (int chk = 0; chk <= 8; chk++) {
        if (chk < 8) {
            // stage 1 for chunk chk (128 p) -> wT[chk&1]; wave w: p_local w*16..+16
            int p0 = chk * 128;
            int prow = p0 + w * 16 + lm;
            f16x8 sa0 = *(const f16x8*)(cb + (size_t)prow * S + lg * 8);
            f16x8 sa1 = *(const f16x8*)(cb + (size_t)prow * S + 32 + lg * 8);
            float d2r[4], avr[4];
            for (int rr = 0; rr < 4; rr++) {
                d2r[rr] = dp2s[p0 + w * 16 + lg * 4 + rr];
                avr[rr] = a2s[p0 + w * 16 + lg * 4 + rr];
            }
            for (int j = 0; j < 4; j++) {
                f16x8 bb0 = lds_ld8(&bT[j * 16 + lm][lg * 8]);
                f16x8 bb1 = lds_ld8(&bT[j * 16 + lm][32 + lg * 8]);
                f32x4 sg = {};
                sg = MFMA(sa0, bb0, sg);
                sg = MFMA(sa1, bb1, sg);
                float wgt[4];
                for (int rr = 0; rr < 4; rr++) {
                    float wc  = EXP2(d2r[rr] * ev[j] - mcv[j]) * izcv[j];
                    float wsv = EXP2(avr[rr] * bqv[j] * sg[rr] - msv[j]) * izsv[j];
                    wgt[rr] = wc + wsv;
                }
                int ql = j * 16 + lm;
                int pp = w * 16 + lg * 4;
                union { f16 h[2]; unsigned u; } c0u, c1u;
                c0u.h[0] = (f16)wgt[0]; c0u.h[1] = (f16)wgt[1];
                c1u.h[0] = (f16)wgt[2]; c1u.h[1] = (f16)wgt[3];
                *(unsigned*)&wT[chk & 1][ql][pp]     = c0u.u;
                *(unsigned*)&wT[chk & 1][ql][pp + 2] = c1u.u;
            }
        }
        if (chk > 0) {
            // stage 2 for chunk chk-1 from wT[(chk-1)&1]; K = 128
            int p0 = (chk - 1) * 128;
            int cur = (chk - 1) & 1;
            for (int ks = 0; ks < 4; ks++) {
                f16x8 a2f[2];
                for (int cf = 0; cf < 2; cf++) {
                    int crow = w * 32 + cf * 16 + lm;
                    a2f[cf] = *(const f16x8*)(sb + (size_t)crow * HW + p0 + ks * 32 + lg * 8);
                }
                for (int qf = 0; qf < 4; qf++) {
                    f16x8 bb = lds_ld8(&wT[cur][qf * 16 + lm][ks * 32 + lg * 8]);
                    acc[0][qf] = MFMA(a2f[0], bb, acc[0][qf]);
                    acc[1][qf] = MFMA(a2f[1], bb, acc[1][qf]);
                }
            }
        }
        __syncthreads();
    }
    for (int cf = 0; cf < 2; cf++)
        for (int qf = 0; qf < 4; qf++) {
            int crow = w * 32 + cf * 16 + lg * 4;
            size_t qrow = (size_t)n * HW + q0 + qf * 16 + lm;
            union { f16 h[2]; unsigned u; } c0u, c1u;
            c0u.h[0] = (f16)acc[cf][qf][0]; c0u.h[1] = (f16)acc[cf][qf][1];
            c1u.h[0] = (f16)acc[cf][qf][2]; c1u.h[1] = (f16)acc[cf][qf][3];
            *(unsigned*)(simT + qrow * C + crow)     = c0u.u;
            *(unsigned*)(simT + qrow * C + crow + 2) = c1u.u;
        }
}

// ---------- out = relu(Wg @ seg_sim + bg) + 2*seg_ori (f16 seg copy) ----------
__global__ void __launch_bounds__(512) k_out(const f16* Wgf, const f16* simT,
        const float* bg, const f16* segf, float* out) {
    int n = blockIdx.x, q0 = blockIdx.y * 64;   // n-major grid (32, 16)
    int tid = threadIdx.x, w = tid >> 6, lane = tid & 63, lm = lane & 15, lg = lane >> 4;
    int ow = (w & 3) * 64, qh = (w >> 2) * 32;
    f32x4 acc[4][2] = {};
    for (int ck = 0; ck < 8; ck++) {
        int c0 = ck * 32;
        f16x8 af[4], bf[2];
        for (int of = 0; of < 4; of++)
            af[of] = *(const f16x8*)(Wgf + (size_t)(ow + of * 16 + lm) * C + c0 + lg * 8);
        for (int qf = 0; qf < 2; qf++)
            bf[qf] = *(const f16x8*)(simT + ((size_t)n * HW + q0 + qh + qf * 16 + lm) * C + c0 + lg * 8);
        for (int of = 0; of < 4; of++)
            for (int qf = 0; qf < 2; qf++)
                acc[of][qf] = MFMA(af[of], bf[qf], acc[of][qf]);
    }
    for (int of = 0; of < 4; of++)
        for (int rr = 0; rr < 4; rr++) {
            int o = ow + of * 16 + lg * 4 + rr;
            float bgv = bg[o];
            for (int qf = 0; qf < 2; qf++) {
                int q = q0 + qh + qf * 16 + lm;
                size_t ix = ((size_t)n * C + o) * HW + q;
                out[ix] = fmaxf(acc[of][qf][rr] + bgv, 0.f) + 2.f * (float)segf[ix];
            }
        }
}

extern "C" void kernel_launch(void* const* d_in, const int* in_sizes, int n_in,
                              void* d_out, int out_size, void* d_ws, size_t ws_size,
                              hipStream_t stream) {
    const float* seg  = (const float*)d_in[0];
    const float* edge = (const float*)d_in[1];
    const float* Ws1  = (const float*)d_in[2];
    const float* bs1  = (const float*)d_in[3];
    const float* Ws11 = (const float*)d_in[4];
    const float* bs11 = (const float*)d_in[5];
    const float* Wmlp = (const float*)d_in[6];
    const float* bmlp = (const float*)d_in[7];
    const float* ws2  = (const float*)d_in[8];
    const float* bs2  = (const float*)d_in[9];
    const float* ws3  = (const float*)d_in[10];
    const float* bs3  = (const float*)d_in[11];
    const float* Wg   = (const float*)d_in[12];
    const float* bg   = (const float*)d_in[13];
    float* out = (float*)d_out;
    char* wsb = (char*)d_ws;

    f16*   segf   = (f16*)(wsb);                   // 16777216 B
    f16*   segc   = (f16*)(wsb + 16777216);        //  4194304 B
    f16*   segs16 = (f16*)(wsb + 20971520);        //  4194304 B
    f16*   simT   = (f16*)(wsb + 25165824);        // 16777216 B
    // pms/pme overlay the simT region (dead until k_fused writes it)
    float* pms    = (float*)(wsb + 25165824);             // 4 MB
    float* pme    = (float*)(wsb + 29360128);             // 4 MB
    f16*   Wf     = (f16*)(wsb + 41943040);        //    65536 B
    f16*   Wgf    = (f16*)(wsb + 42008576);        //   131072 B
    float* mean   = (float*)(wsb + 42139648);      //    32768 B
    float* chat   = (float*)(wsb + 42172416);      //     8192 B
    float* dp2    = (float*)(wsb + 42180608);      //   131072 B
    float* e_     = (float*)(wsb + 42311680);
    float* a2     = (float*)(wsb + 42442752);
    float* bq     = (float*)(wsb + 42573824);
    float* Mc2    = (float*)(wsb + 42704896);
    float* iZc    = (float*)(wsb + 42835968);
    float* Ms2    = (float*)(wsb + 42967040);
    float* iZs    = (float*)(wsb + 43098112);
    float* dpmm2  = (float*)(wsb + 43229184);      //     2048 B

    k_pool1<<<dim3(32, 32), 256, 0, stream>>>(seg, edge, segf, pms, pme, mean,
                                              Ws1, Ws11, Wg, Wf, Wgf);
    k_pool2<<<32, 256, 0, stream>>>(pms, pme, a2, bq, ws2, bs2, ws3, bs3,
                                    mean, Wmlp, bmlp, chat);
    k_proj<<<dim3(32, 16), 512, 0, stream>>>(segf, Wf, bs1, bs11, segs16, segc);
    k_dp<<<dim3(32, 8), 256, 0, stream>>>(segs16, chat, dp2, e_, dpmm2);
    k_zc<<<dim3(32, 32), 256, 0, stream>>>(dp2, e_, dpmm2, Mc2, iZc);
    k_sstats<<<dim3(32, 32), 512, 0, stream>>>(segc, a2, bq, Ms2, iZs);
    k_fused<<<dim3(32, 16), 512, 0, stream>>>(segf, segc, dp2, e_, a2, bq,
                                              Mc2, iZc, Ms2, iZs, simT);
    k_out<<<dim3(32, 16), 512, 0, stream>>>(Wgf, simT, bg, segf, out);
}

// Round 10
// 249.298 us; speedup vs baseline: 1.3858x; 1.0852x over previous
//
#include <hip/hip_runtime.h>

#define N 32
#define C 256
#define HW 1024
#define S 64
#define LOG2E 1.4426950408889634f

typedef _Float16 f16;
typedef _Float16 f16x4 __attribute__((ext_vector_type(4)));
typedef _Float16 f16x8 __attribute__((ext_vector_type(8)));
typedef float f32x4 __attribute__((ext_vector_type(4)));

#define MFMA(a, b, c) __builtin_amdgcn_mfma_f32_16x16x32_f16(a, b, c, 0, 0, 0)
#define EXP2(x) exp2f(x)

// 8B-aligned LDS f16x8 load (two ds_read_b64)
__device__ inline f16x8 lds_ld8(const f16* p) {
    f16x4 a = *(const f16x4*)p;
    f16x4 b = *(const f16x4*)(p + 4);
    f16x8 r;
    r[0] = a[0]; r[1] = a[1]; r[2] = a[2]; r[3] = a[3];
    r[4] = b[0]; r[5] = b[1]; r[6] = b[2]; r[7] = b[3];
    return r;
}

// ---------- pool pass 1 (+ weight conversion fold): float4 stream ----------
__global__ void __launch_bounds__(256) k_pool1(const float* seg, const float* edge,
        f16* segf, float* pms, float* pme, float* mean,
        const float* Ws1, const float* Ws11, const float* Wg, f16* Wf, f16* Wgf) {
    int n = blockIdx.x, cg = blockIdx.y;          // grid (32, 32), 8 c per block
    int t = threadIdx.x, w = t >> 6, lane = t & 63;
    int flat = n * 32 + cg;
    if (flat < 256) {                              // weight conversion fold
        int i = flat * 256 + t;
        if (i < S * C) { Wf[i] = (f16)Ws1[i]; Wf[S * C + i] = (f16)Ws11[i]; }
        Wgf[i] = (f16)Wg[i];
    }
    int p4 = (lane << 2) + (w << 8);
    size_t base = (size_t)n * C * HW;
    float4 ms = make_float4(-3e38f, -3e38f, -3e38f, -3e38f);
    float4 me = ms;
    __shared__ float psum[4][8];
    for (int ci = 0; ci < 8; ci++) {
        int c = cg * 8 + ci;
        size_t off = base + (size_t)c * HW + p4;
        float4 s = *(const float4*)(seg + off);
        float4 e = *(const float4*)(edge + off);
        union { f16 h[4]; unsigned long long u; } pk;
        pk.h[0] = (f16)s.x; pk.h[1] = (f16)s.y; pk.h[2] = (f16)s.z; pk.h[3] = (f16)s.w;
        *(unsigned long long*)(segf + off) = pk.u;
        ms.x = fmaxf(ms.x, s.x); ms.y = fmaxf(ms.y, s.y);
        ms.z = fmaxf(ms.z, s.z); ms.w = fmaxf(ms.w, s.w);
        me.x = fmaxf(me.x, s.x * e.x); me.y = fmaxf(me.y, s.y * e.y);
        me.z = fmaxf(me.z, s.z * e.z); me.w = fmaxf(me.w, s.w * e.w);
        float sm = s.x + s.y + s.z + s.w;
        for (int o = 32; o; o >>= 1) sm += __shfl_down(sm, o);
        if (lane == 0) psum[w][ci] = sm;
    }
    __syncthreads();
    if (t < 8)
        mean[n * C + cg * 8 + t] =
            (psum[0][t] + psum[1][t] + psum[2][t] + psum[3][t]) * (1.0f / HW);
    size_t pb = ((size_t)n * 32 + cg) * HW + p4;
    *(float4*)(pms + pb) = ms;
    *(float4*)(pme + pb) = me;
}

// ---------- pool pass 2 (+ ch_att fold) ----------
__global__ void __launch_bounds__(256) k_pool2(const float* pms, const float* pme,
        float* a2, float* bq, const float* ws2, const float* bs2,
        const float* ws3, const float* bs3,
        const float* mean, const float* Wmlp, const float* bmlp, float* chat) {
    int n = blockIdx.x, t = threadIdx.x;
    int p4 = t << 2;
    float4 ms = make_float4(-3e38f, -3e38f, -3e38f, -3e38f);
    float4 me = ms;
    for (int cg = 0; cg < 32; cg++) {
        size_t pb = ((size_t)n * 32 + cg) * HW + p4;
        float4 a = *(const float4*)(pms + pb);
        float4 b = *(const float4*)(pme + pb);
        ms.x = fmaxf(ms.x, a.x); ms.y = fmaxf(ms.y, a.y);
        ms.z = fmaxf(ms.z, a.z); ms.w = fmaxf(ms.w, a.w);
        me.x = fmaxf(me.x, b.x); me.y = fmaxf(me.y, b.y);
        me.z = fmaxf(me.z, b.z); me.w = fmaxf(me.w, b.w);
    }
    float w3 = ws3[0], b3 = bs3[0], w2 = ws2[0], b2 = bs2[0];
    float4 av, bv;
    av.x = (me.x * w3 + b3) * LOG2E; av.y = (me.y * w3 + b3) * LOG2E;
    av.z = (me.z * w3 + b3) * LOG2E; av.w = (me.w * w3 + b3) * LOG2E;
    bv.x = ms.x * w2 + b2; bv.y = ms.y * w2 + b2;
    bv.z = ms.z * w2 + b2; bv.w = ms.w * w2 + b2;
    *(float4*)(a2 + (size_t)n * HW + p4) = av;
    *(float4*)(bq + (size_t)n * HW + p4) = bv;
    if (t < S) {            // ch_att fold (reads k_pool1's mean)
        float acc = 0.f;
        const float* wr = Wmlp + (size_t)t * C;
        for (int c = 0; c < C; c++) acc += mean[n * C + c] * wr[c];
        chat[n * S + t] = fmaxf(acc + bmlp[t], 0.f);
    }
}

// ---------- projections (+ folded k_dp: dp2, e, partial max/min) ----------
// Block (n, qt) covers q-tile [qt*64, +64). The flat-reshape theta strip for
// p = 16r + qt lies entirely inside this tile (64*(p&15) == q0), so dp2/e are
// computed here from an LDS copy of the seg_s rows; segs16 never hits global.
__global__ void __launch_bounds__(512) k_proj(const f16* segf, const f16* Wf,
        const float* bs1, const float* bs11, const float* chat,
        f16* segc, float* dp2, float* e_, float* dpmm2) {
    int n = blockIdx.x, qt = blockIdx.y;   // grid (32, 16)
    int q0 = qt * 64;
    __shared__ f16 sT[64][260];   // [q][c] staging
    __shared__ f16 pT[64][68];    // seg_s tile [row][q_local]
    __shared__ float cA[S];
    const f16* sb = segf + (size_t)n * C * HW + q0;
    int tid = threadIdx.x;
    if (tid < S) cA[tid] = chat[n * S + tid];
    for (int idx = tid; idx < 2048; idx += 512) {
        int c = idx >> 3, q8 = (idx & 7) << 3;
        f16x8 v = *(const f16x8*)(sb + (size_t)c * HW + q8);
        for (int j = 0; j < 8; j++) sT[q8 + j][c] = v[j];
    }
    __syncthreads();
    int lane = tid & 63, wv = tid >> 6;
    int lm = lane & 15, lg = lane >> 4;
    f32x4 acc[4] = {};
    for (int ck = 0; ck < 8; ck++) {
        int c0 = ck * 32;
        f16x8 a0 = *(const f16x8*)(Wf + (size_t)(wv * 16 + lm) * C + c0 + lg * 8);
        for (int j = 0; j < 4; j++) {
            f16x8 b = lds_ld8(&sT[j * 16 + lm][c0 + lg * 8]);
            acc[j] = MFMA(a0, b, acc[j]);
        }
    }
    for (int rr = 0; rr < 4; rr++) {
        int row = wv * 16 + lg * 4 + rr;
        float bias = (row < S) ? bs1[row] : bs11[row - S];
        for (int j = 0; j < 4; j++) {
            int q = q0 + j * 16 + lm;
            float v = acc[j][rr] + bias;
            if (row < S) pT[row][j * 16 + lm] = (f16)v;
            else         segc[((size_t)n * S + (row - S)) * HW + q] = (f16)v;
        }
    }
    __syncthreads();
    if (tid < 64) {
        // dp2[p], p = 16*tid + qt : contiguous 64-strip = pT row tid
        float a2c = 0.f;
        for (int t = 0; t < S; t += 8) {
            f16x8 v = lds_ld8(&pT[tid][t]);
            for (int j = 0; j < 8; j++) a2c += (float)v[j] * cA[t + j];
        }
        float d2 = a2c * LOG2E;
        dp2[(size_t)n * HW + 16 * tid + qt] = d2;
        float mx = d2, mn = d2;
        for (int o = 32; o; o >>= 1) {
            mx = fmaxf(mx, __shfl_down(mx, o));
            mn = fminf(mn, __shfl_down(mn, o));
        }
        if (tid == 0) {
            dpmm2[(n * 16 + qt) * 2]     = mx;
            dpmm2[(n * 16 + qt) * 2 + 1] = mn;
        }
    } else if (tid < 128) {
        int ql = tid - 64;     // e[q] = sum_t chat[t] * seg_s[t][q]
        float a2c = 0.f;
        for (int t = 0; t < S; t++) a2c += cA[t] * (float)pT[t][ql];
        e_[(size_t)n * HW + q0 + ql] = a2c;
    }
}

// ---------- sim_c softmax stats (Mc, 1/Zc); grid (32,32), 8 thr/q ----------
__global__ void __launch_bounds__(256) k_zc(const float* dp2, const float* e_,
        const float* dpmm2, float* Mc2, float* iZc) {
    int n = blockIdx.x, g = blockIdx.y, t = threadIdx.x;
    __shared__ float d[HW];
    for (int i = t; i < HW; i += 256) d[i] = dp2[(size_t)n * HW + i];
    float mx = -3e38f, mn = 3e38f;
    for (int j = 0; j < 16; j++) {
        mx = fmaxf(mx, dpmm2[(n * 16 + j) * 2]);
        mn = fminf(mn, dpmm2[(n * 16 + j) * 2 + 1]);
    }
    __syncthreads();
    int q = g * 32 + (t >> 3);      // 32 q per block
    int pi = t & 7;
    float eq = e_[(size_t)n * HW + q];
    float m = (eq > 0.f) ? eq * mx : eq * mn;
    float z = 0.f;
    for (int j = 0; j < 128; j++) z += EXP2(d[pi + 8 * j] * eq - m);
    z += __shfl_xor(z, 1);
    z += __shfl_xor(z, 2);
    z += __shfl_xor(z, 4);
    if (pi == 0) {
        Mc2[(size_t)n * HW + q] = m;
        iZc[(size_t)n * HW + q] = 1.f / z;
    }
}

// ---------- sim_s softmax stats (Ms, 1/Ls); p 4-way split; grid (32, 32) ----------
__global__ void __launch_bounds__(512) k_sstats(const f16* segc, const float* a2,
        const float* bq, float* Ms2, float* iZs) {
    int n = blockIdx.x, q0 = blockIdx.y * 32;
    __shared__ f16 bT[32][68];
    __shared__ float a2s[HW];
    __shared__ float mred[32][4], lred[32][4];
    const f16* cb = segc + (size_t)n * S * HW;
    int tid = threadIdx.x;
    if (tid < 256) {
        int th = tid >> 2, q8 = (tid & 3) << 3;
        f16x8 v = *(const f16x8*)(cb + (size_t)th * HW + q0 + q8);
        for (int j = 0; j < 8; j++) bT[q8 + j][th] = v[j];
    }
    for (int i = tid; i < HW; i += 512) a2s[i] = a2[(size_t)n * HW + i];
    __syncthreads();
    int w = tid >> 6, lane = tid & 63, lm = lane & 15, lg = lane >> 4;
    int qg = w >> 2, ph = w & 3;   // 2 q-groups x 4 p-quarters
    f16x8 b0 = lds_ld8(&bT[qg * 16 + lm][lg * 8]);
    f16x8 b1 = lds_ld8(&bT[qg * 16 + lm][32 + lg * 8]);
    float bqv = bq[(size_t)n * HW + q0 + qg * 16 + lm];
    float m = -3e38f, l = 0.f;
    for (int it = 0; it < 8; it++) {
        int pb = ph * 256 + it * 32;
        f16x8 a0 = *(const f16x8*)(cb + (size_t)(pb + lm) * S + lg * 8);
        f16x8 a1 = *(const f16x8*)(cb + (size_t)(pb + lm) * S + 32 + lg * 8);
        f16x8 c0 = *(const f16x8*)(cb + (size_t)(pb + 16 + lm) * S + lg * 8);
        f16x8 c1 = *(const f16x8*)(cb + (size_t)(pb + 16 + lm) * S + 32 + lg * 8);
        f32x4 sgA = {}, sgB = {};
        sgA = MFMA(a0, b0, sgA); sgA = MFMA(a1, b1, sgA);
        sgB = MFMA(c0, b0, sgB); sgB = MFMA(c1, b1, sgB);
        float sc[8];
        float fm = -3e38f;
        for (int rr = 0; rr < 4; rr++) {
            float avA = a2s[pb + lg * 4 + rr];
            float avB = a2s[pb + 16 + lg * 4 + rr];
            sc[rr]     = avA * bqv * sgA[rr];
            sc[rr + 4] = avB * bqv * sgB[rr];
            fm = fmaxf(fm, fmaxf(sc[rr], sc[rr + 4]));
        }
        fm = fmaxf(fm, __shfl_xor(fm, 16));
        fm = fmaxf(fm, __shfl_xor(fm, 32));
        float fl = 0.f;
        for (int rr = 0; rr < 8; rr++) fl += EXP2(sc[rr] - fm);
        fl += __shfl_xor(fl, 16);
        fl += __shfl_xor(fl, 32);
        float nm = fmaxf(m, fm);
        l = l * EXP2(m - nm) + fl * EXP2(fm - nm);
        m = nm;
    }
    if (lg == 0) { mred[qg * 16 + lm][ph] = m; lred[qg * 16 + lm][ph] = l; }
    __syncthreads();
    if (tid < 32) {
        float M = fmaxf(fmaxf(mred[tid][0], mred[tid][1]),
                        fmaxf(mred[tid][2], mred[tid][3]));
        float L = lred[tid][0] * EXP2(mred[tid][0] - M)
                + lred[tid][1] * EXP2(mred[tid][1] - M)
                + lred[tid][2] * EXP2(mred[tid][2] - M)
                + lred[tid][3] * EXP2(mred[tid][3] - M);
        Ms2[(size_t)n * HW + q0 + tid] = M;
        iZs[(size_t)n * HW + q0 + tid] = 1.f / L;
    }
}

// ---------- fused: sigma -> weights -> seg_sim -> Wg GEMM -> out ----------
// q-tile 64, BK=128, dbuf wT, (512,4): measured VGPR 64 / no spill.
// M-subtraction kept IN the exponent (round-6 overflow bug).
// k_out folded: block holds full C=256 of seg_sim for its q-tile; acc -> LDS
// (overlaying dead wT dbuf), then Wg GEMM + relu + residual + direct store.
__global__ void __launch_bounds__(512, 4) k_fused(const f16* segf, const f16* segc,
        const float* dp2, const float* e_, const float* a2, const float* bq,
        const float* Mc2, const float* iZc, const float* Ms2, const float* iZs,
        const f16* Wgf, const float* bg, float* out) {
    int n = blockIdx.x, q0 = blockIdx.y * 64;   // n-major grid (32, 16)
    __shared__ f16 bT[64][68];        // segc^T tile [q][t]
    __shared__ f16 wT[2][64][132];    // dbuf weight tile [q][p_local]
    __shared__ float dp2s[HW], a2s[HW];
    const f16* cb = segc + (size_t)n * S * HW;
    const f16* sb = segf + (size_t)n * C * HW;
    int tid = threadIdx.x;
    for (int idx = tid; idx < 64 * 32; idx += 512) {
        int q = idx & 63, th = (idx >> 6) << 1;
        union { f16 h[2]; unsigned u; } pk;
        pk.h[0] = cb[(size_t)th * HW + q0 + q];
        pk.h[1] = cb[(size_t)(th + 1) * HW + q0 + q];
        *(unsigned*)&bT[q][th] = pk.u;
    }
    for (int i = tid; i < HW; i += 512) {
        dp2s[i] = dp2[(size_t)n * HW + i];
        a2s[i]  = a2[(size_t)n * HW + i];
    }
    __syncthreads();
    int w = tid >> 6, lane = tid & 63, lm = lane & 15, lg = lane >> 4;
    float ev[4], bqv[4], mcv[4], izcv[4], msv[4], izsv[4];
    for (int j = 0; j < 4; j++) {
        size_t gq = (size_t)n * HW + q0 + j * 16 + lm;
        ev[j] = e_[gq];  bqv[j] = bq[gq];
        mcv[j] = Mc2[gq]; izcv[j] = iZc[gq];
        msv[j] = Ms2[gq]; izsv[j] = iZs[gq];
    }
    f32x4 acc[2][4] = {};   // 32 c-rows (w*32) x 64 q
    for (int chk = 0; chk <= 8; chk++) {
        if (chk < 8) {
            int p0 = chk * 128;
            int prow = p0 + w * 16 + lm;
            f16x8 sa0 = *(const f16x8*)(cb + (size_t)prow * S + lg * 8);
            f16x8 sa1 = *(const f16x8*)(cb + (size_t)prow * S + 32 + lg * 8);
            float d2r[4], avr[4];
            for (int rr = 0; rr < 4; rr++) {
                d2r[rr] = dp2s[p0 + w * 16 + lg * 4 + rr];
                avr[rr] = a2s[p0 + w * 16 + lg * 4 + rr];
            }
            for (int j = 0; j < 4; j++) {
                f16x8 bb0 = lds_ld8(&bT[j * 16 + lm][lg * 8]);
                f16x8 bb1 = lds_ld8(&bT[j * 16 + lm][32 + lg * 8]);
                f32x4 sg = {};
                sg = MFMA(sa0, bb0, sg);
                sg = MFMA(sa1, bb1, sg);
                float wgt[4];
                for (int rr = 0; rr < 4; rr++) {
                    float wc  = EXP2(d2r[rr] * ev[j] - mcv[j]) * izcv[j];
                    float wsv = EXP2(avr[rr] * bqv[j] * sg[rr] - msv[j]) * izsv[j];
                    wgt[rr] = wc + wsv;
                }
                int ql = j * 16 + lm;
                int pp = w * 16 + lg * 4;
                union { f16 h[2]; unsigned u; } c0u, c1u;
                c0u.h[0] = (f16)wgt[0]; c0u.h[1] = (f16)wgt[1];
                c1u.h[0] = (f16)wgt[2]; c1u.h[1] = (f16)wgt[3];
                *(unsigned*)&wT[chk & 1][ql][pp]     = c0u.u;
                *(unsigned*)&wT[chk & 1][ql][pp + 2] = c1u.u;
            }
        }
        if (chk > 0) {
            int p0 = (chk - 1) * 128;
            int cur = (chk - 1) & 1;
            for (int ks = 0; ks < 4; ks++) {
                f16x8 a2f[2];
                for (int cf = 0; cf < 2; cf++) {
                    int crow = w * 32 + cf * 16 + lm;
                    a2f[cf] = *(const f16x8*)(sb + (size_t)crow * HW + p0 + ks * 32 + lg * 8);
                }
                for (int qf = 0; qf < 4; qf++) {
                    f16x8 bb = lds_ld8(&wT[cur][qf * 16 + lm][ks * 32 + lg * 8]);
                    acc[0][qf] = MFMA(a2f[0], bb, acc[0][qf]);
                    acc[1][qf] = MFMA(a2f[1], bb, acc[1][qf]);
                }
            }
        }
        __syncthreads();
    }
    // ---- folded k_out epilogue: seg_sim tile -> LDS (overlay dead wT) ----
    f16 (*sT2)[260] = (f16(*)[260])&wT[0][0][0];   // 64*260*2 = 33280 <= 33792 B
    for (int cf = 0; cf < 2; cf++)
        for (int qf = 0; qf < 4; qf++) {
            int crow = w * 32 + cf * 16 + lg * 4;
            int ql = qf * 16 + lm;
            f16x4 pk;
            pk[0] = (f16)acc[cf][qf][0]; pk[1] = (f16)acc[cf][qf][1];
            pk[2] = (f16)acc[cf][qf][2]; pk[3] = (f16)acc[cf][qf][3];
            *(f16x4*)&sT2[ql][crow] = pk;
        }
    __syncthreads();
    int ow = w * 32;
    f32x4 acc2[2][4] = {};
    for (int ck = 0; ck < 8; ck++) {
        int c0 = ck * 32;
        f16x8 af0 = *(const f16x8*)(Wgf + (size_t)(ow + lm) * C + c0 + lg * 8);
        f16x8 af1 = *(const f16x8*)(Wgf + (size_t)(ow + 16 + lm) * C + c0 + lg * 8);
        for (int qf = 0; qf < 4; qf++) {
            f16x8 bf = lds_ld8(&sT2[qf * 16 + lm][c0 + lg * 8]);
            acc2[0][qf] = MFMA(af0, bf, acc2[0][qf]);
            acc2[1][qf] = MFMA(af1, bf, acc2[1][qf]);
        }
    }
    for (int of = 0; of < 2; of++)
        for (int rr = 0; rr < 4; rr++) {
            int o = ow + of * 16 + lg * 4 + rr;
            float bgv = bg[o];
            for (int qf = 0; qf < 4; qf++) {
                int q = q0 + qf * 16 + lm;
                size_t ix = ((size_t)n * C + o) * HW + q;
                out[ix] = fmaxf(acc2[of][qf][rr] + bgv, 0.f) + 2.f * (float)sb[((size_t)o * HW) + q];
            }
        }
}

extern "C" void kernel_launch(void* const* d_in, const int* in_sizes, int n_in,
                              void* d_out, int out_size, void* d_ws, size_t ws_size,
                              hipStream_t stream) {
    const float* seg  = (const float*)d_in[0];
    const float* edge = (const float*)d_in[1];
    const float* Ws1  = (const float*)d_in[2];
    const float* bs1  = (const float*)d_in[3];
    const float* Ws11 = (const float*)d_in[4];
    const float* bs11 = (const float*)d_in[5];
    const float* Wmlp = (const float*)d_in[6];
    const float* bmlp = (const float*)d_in[7];
    const float* ws2  = (const float*)d_in[8];
    const float* bs2  = (const float*)d_in[9];
    const float* ws3  = (const float*)d_in[10];
    const float* bs3  = (const float*)d_in[11];
    const float* Wg   = (const float*)d_in[12];
    const float* bg   = (const float*)d_in[13];
    float* out = (float*)d_out;
    char* wsb = (char*)d_ws;

    f16*   segf   = (f16*)(wsb);                   // 16777216 B
    f16*   segc   = (f16*)(wsb + 16777216);        //  4194304 B
    float* dpmm2  = (float*)(wsb + 20971520);      //  4096 B (old segs16 slot)
    // pms/pme overlay the old simT region (free scratch)
    float* pms    = (float*)(wsb + 25165824);             // 4 MB
    float* pme    = (float*)(wsb + 29360128);             // 4 MB
    f16*   Wf     = (f16*)(wsb + 41943040);        //    65536 B
    f16*   Wgf    = (f16*)(wsb + 42008576);        //   131072 B
    float* mean   = (float*)(wsb + 42139648);      //    32768 B
    float* chat   = (float*)(wsb + 42172416);      //     8192 B
    float* dp2    = (float*)(wsb + 42180608);      //   131072 B
    float* e_     = (float*)(wsb + 42311680);
    float* a2     = (float*)(wsb + 42442752);
    float* bq     = (float*)(wsb + 42573824);
    float* Mc2    = (float*)(wsb + 42704896);
    float* iZc    = (float*)(wsb + 42835968);
    float* Ms2    = (float*)(wsb + 42967040);
    float* iZs    = (float*)(wsb + 43098112);

    k_pool1<<<dim3(32, 32), 256, 0, stream>>>(seg, edge, segf, pms, pme, mean,
                                              Ws1, Ws11, Wg, Wf, Wgf);
    k_pool2<<<32, 256, 0, stream>>>(pms, pme, a2, bq, ws2, bs2, ws3, bs3,
                                    mean, Wmlp, bmlp, chat);
    k_proj<<<dim3(32, 16), 512, 0, stream>>>(segf, Wf, bs1, bs11, chat,
                                             segc, dp2, e_, dpmm2);
    k_zc<<<dim3(32, 32), 256, 0, stream>>>(dp2, e_, dpmm2, Mc2, iZc);
    k_sstats<<<dim3(32, 32), 512, 0, stream>>>(segc, a2, bq, Ms2, iZs);
    k_fused<<<dim3(32, 16), 512, 0, stream>>>(segf, segc, dp2, e_, a2, bq,
                                              Mc2, iZc, Ms2, iZs, Wgf, bg, out);
}